// Round 1
// baseline (6497.459 us; speedup 1.0000x reference)
//
#include <hip/hip_runtime.h>
#include <cmath>

// Problem constants
#define BB 2
#define SS_ 2048
#define EE 1024
#define CC 16
#define HH 16

// ---------------------------------------------------------------------------
// Generic tiled fp32 GEMM: C = alpha * A @ B(^T) [+ beta*C] [+ bias[n]]
// A: (M,K) row-major, lda
// TRANSB: Bsrc (N,K) row-major (ldb=K-ish)  => B(k,n) = Bsrc[n*ldb+k]
// else  : Bsrc (K,N) row-major              => B(k,n) = Bsrc[k*ldb+n]
// Batched via blockIdx.z with element strides sA/sB/sC (sA may be 0 = broadcast).
// Requires M%128==0, N%128==0, K%16==0, all pointers/ld 16B-friendly.
// ---------------------------------------------------------------------------
#define TM 128
#define TN 128
#define TK 16

template<bool TRANSB, bool BETA, bool BIAS>
__launch_bounds__(256)
__global__ void gemm_kernel(const float* __restrict__ A, const float* __restrict__ Bsrc,
                            float* __restrict__ C, const float* __restrict__ bias,
                            int M, int N, int K, int lda, int ldb, int ldc,
                            long sA, long sB, long sC, float alpha, float beta)
{
    __shared__ float As[TK][TM + 4];
    __shared__ float Bs[TK][TN + 4];
    const int bz = blockIdx.z;
    A += (size_t)bz * sA; Bsrc += (size_t)bz * sB; C += (size_t)bz * sC;
    const int tid = threadIdx.x;
    const int m0 = blockIdx.y * TM, n0 = blockIdx.x * TN;
    const int tr = tid >> 4, tc = tid & 15;
    float acc[8][8] = {};
    for (int k0 = 0; k0 < K; k0 += TK) {
        #pragma unroll
        for (int ch = 0; ch < 2; ++ch) {
            int lin = ch * 256 + tid;          // float4 id, 0..511
            int m = lin >> 2, j4 = (lin & 3) * 4;
            const float4 v = *(const float4*)(A + (size_t)(m0 + m) * lda + k0 + j4);
            As[j4 + 0][m] = v.x; As[j4 + 1][m] = v.y; As[j4 + 2][m] = v.z; As[j4 + 3][m] = v.w;
        }
        if (TRANSB) {
            #pragma unroll
            for (int ch = 0; ch < 2; ++ch) {
                int lin = ch * 256 + tid;
                int n = lin >> 2, j4 = (lin & 3) * 4;
                const float4 v = *(const float4*)(Bsrc + (size_t)(n0 + n) * ldb + k0 + j4);
                Bs[j4 + 0][n] = v.x; Bs[j4 + 1][n] = v.y; Bs[j4 + 2][n] = v.z; Bs[j4 + 3][n] = v.w;
            }
        } else {
            #pragma unroll
            for (int ch = 0; ch < 2; ++ch) {
                int lin = ch * 256 + tid;
                int kk = lin >> 5, n4 = (lin & 31) * 4;
                *(float4*)&Bs[kk][n4] = *(const float4*)(Bsrc + (size_t)(k0 + kk) * ldb + n0 + n4);
            }
        }
        __syncthreads();
        #pragma unroll
        for (int kk = 0; kk < TK; ++kk) {
            float a[8], b[8];
            *(float4*)&a[0] = *(const float4*)&As[kk][tr * 8];
            *(float4*)&a[4] = *(const float4*)&As[kk][tr * 8 + 4];
            *(float4*)&b[0] = *(const float4*)&Bs[kk][tc * 8];
            *(float4*)&b[4] = *(const float4*)&Bs[kk][tc * 8 + 4];
            #pragma unroll
            for (int i = 0; i < 8; ++i)
                #pragma unroll
                for (int j = 0; j < 8; ++j)
                    acc[i][j] += a[i] * b[j];
        }
        __syncthreads();
    }
    #pragma unroll
    for (int i = 0; i < 8; ++i) {
        int m = m0 + tr * 8 + i;
        float* crow = C + (size_t)m * ldc + n0 + tc * 8;
        #pragma unroll
        for (int jj = 0; jj < 2; ++jj) {
            float4 v;
            v.x = alpha * acc[i][jj * 4 + 0];
            v.y = alpha * acc[i][jj * 4 + 1];
            v.z = alpha * acc[i][jj * 4 + 2];
            v.w = alpha * acc[i][jj * 4 + 3];
            if (BETA) {
                float4 c0 = *(const float4*)(crow + jj * 4);
                v.x += beta * c0.x; v.y += beta * c0.y; v.z += beta * c0.z; v.w += beta * c0.w;
            }
            if (BIAS) {
                float4 bv = *(const float4*)(bias + n0 + tc * 8 + jj * 4);
                v.x += bv.x; v.y += bv.y; v.z += bv.z; v.w += bv.w;
            }
            *(float4*)(crow + jj * 4) = v;
        }
    }
}

// ---------------------------------------------------------------------------
// DFT twiddle matrices: Ccos[k,n]=cos(2*pi*k*n/S), Sn[k,n]=-sin(2*pi*k*n/S)
// Exact integer reduction (k*n mod 2048) -> high accuracy vs reference FFT.
// ---------------------------------------------------------------------------
__global__ void gen_dft(float* __restrict__ Cc, float* __restrict__ Sn)
{
    size_t idx = (size_t)blockIdx.x * 256 + threadIdx.x;   // S*S = 4194304
    int k = (int)(idx >> 11);
    int n = (int)(idx & 2047);
    int m = (k * n) & 2047;
    float ang = (float)(6.283185307179586 * (double)m / 2048.0);
    Cc[idx] = cosf(ang);
    Sn[idx] = -sinf(ang);
}

// DCT-II matrices, mimicking the reference's fp32 arithmetic order.
__global__ void gen_dct(float* __restrict__ D, float* __restrict__ I)
{
    size_t idx = (size_t)blockIdx.x * 256 + threadIdx.x;   // L*L
    int i = (int)(idx >> 11);
    int j = (int)(idx & 2047);
    const float r1 = 0.022097086912079608f;  // float32(sqrt(1/2048))
    const float r2 = 0.03125f;               // sqrt(2/2048) = 1/32
    const float pif = 3.14159265358979323846f;
    float a  = (pif * (float)i) * (float)(2 * j + 1) / 4096.0f;
    D[idx] = cosf(a) * (i == 0 ? r1 : r2);
    float ai = (pif * (float)j) * (float)(2 * i + 1) / 4096.0f;
    I[idx] = cosf(ai) * (j == 0 ? r1 : r2);
}

// softmax over C=16 channel axis of Fp (C,E) -> fw (C,E)
__global__ void softmax_C(const float* __restrict__ Fp, float* __restrict__ fw)
{
    int e = blockIdx.x * 256 + threadIdx.x;
    if (e >= EE) return;
    float v[CC]; float m = -3.4e38f;
    #pragma unroll
    for (int c = 0; c < CC; ++c) { v[c] = Fp[c * EE + e]; m = fmaxf(m, v[c]); }
    float s = 0.f;
    #pragma unroll
    for (int c = 0; c < CC; ++c) { v[c] = expf(v[c] - m); s += v[c]; }
    float inv = 1.f / s;
    #pragma unroll
    for (int c = 0; c < CC; ++c) fw[c * EE + e] = v[c] * inv;
}

// Wc (C,E,3) -> Wt[(e*3+k)*16 + c]
__global__ void transpose_wc(const float* __restrict__ Wc, float* __restrict__ Wt)
{
    int idx = blockIdx.x * 256 + threadIdx.x;
    if (idx >= CC * EE * 3) return;
    int c = idx / (EE * 3); int rem = idx % (EE * 3); int e = rem / 3; int k = rem % 3;
    Wt[(e * 3 + k) * CC + c] = Wc[idx];
}

// One Haar level: cur rows [0,2h) -> detail rows [h,2h) of det, approx rows [0,h) of nxt
__global__ void haar_level(const float* __restrict__ cur, float* __restrict__ nxt,
                           float* __restrict__ det, int h)
{
    size_t idx = (size_t)blockIdx.x * 256 + threadIdx.x;
    size_t tot = (size_t)BB * h * EE;
    if (idx >= tot) return;
    int e = (int)(idx & (EE - 1));
    size_t t = idx >> 10;
    int i = (int)(t % h);
    int b = (int)(t / h);
    const float SQ2 = 1.41421356237309504880f;
    const size_t SEl = (size_t)SS_ * EE;
    const float* cb = cur + (size_t)b * SEl;
    float ev = cb[(size_t)(2 * i) * EE + e];
    float ov = cb[(size_t)(2 * i + 1) * EE + e];
    det[(size_t)b * SEl + (size_t)(h + i) * EE + e] = (ev - ov) / SQ2;
    nxt[(size_t)b * SEl + (size_t)i * EE + e] = (ev + ov) / SQ2;
}

// ---------------------------------------------------------------------------
// conv1d (3-tap, E->C) + channel mix (C->E with softmaxed fw), TS_CONV s per block
// ---------------------------------------------------------------------------
#define TS_CONV 4
__launch_bounds__(256)
__global__ void conv_channels(const float* __restrict__ X, const float* __restrict__ Wt,
                              const float* __restrict__ bc, const float* __restrict__ fw,
                              float* __restrict__ Out)
{
    __shared__ float xl[TS_CONV + 2][1028];
    __shared__ float chs[TS_CONV][CC];
    __shared__ float red[CC][CC];
    const int blk = blockIdx.x;                 // B * (S/TS_CONV)
    const int spb = SS_ / TS_CONV;
    const int b = blk / spb, s0 = (blk % spb) * TS_CONV;
    const int tid = threadIdx.x;
    const size_t SEl = (size_t)SS_ * EE;
    const float* xb = X + (size_t)b * SEl;
    #pragma unroll
    for (int r = 0; r < TS_CONV + 2; ++r) {
        int sr = s0 - 1 + r;
        float4 v = make_float4(0.f, 0.f, 0.f, 0.f);
        if (sr >= 0 && sr < SS_) v = *(const float4*)(xb + (size_t)sr * EE + tid * 4);
        *(float4*)&xl[r][tid * 4] = v;
    }
    __syncthreads();
    const int c = tid & 15, part = tid >> 4;    // 16 parts x 16 channels
    float acc[TS_CONV] = {0.f, 0.f, 0.f, 0.f};
    for (int i = 0; i < EE / CC; ++i) {
        int e = part + CC * i;
        float x6[TS_CONV + 2];
        #pragma unroll
        for (int r = 0; r < TS_CONV + 2; ++r) x6[r] = xl[r][e];
        #pragma unroll
        for (int k = 0; k < 3; ++k) {
            float w = Wt[(e * 3 + k) * CC + c];
            #pragma unroll
            for (int sl = 0; sl < TS_CONV; ++sl) acc[sl] += x6[sl + k] * w;
        }
    }
    for (int sl = 0; sl < TS_CONV; ++sl) {
        red[part][c] = acc[sl];
        __syncthreads();
        if (tid < CC) {
            float t = bc[tid];
            #pragma unroll
            for (int p = 0; p < CC; ++p) t += red[p][tid];
            chs[sl][tid] = t;
        }
        __syncthreads();
    }
    for (int sl = 0; sl < TS_CONV; ++sl) {
        const int e0 = tid * 4;
        float o0 = 0.f, o1 = 0.f, o2 = 0.f, o3 = 0.f;
        #pragma unroll
        for (int cc2 = 0; cc2 < CC; ++cc2) {
            float cv = chs[sl][cc2];
            const float* fr = fw + cc2 * EE + e0;
            o0 += cv * fr[0]; o1 += cv * fr[1]; o2 += cv * fr[2]; o3 += cv * fr[3];
        }
        *(float4*)(Out + (size_t)b * SEl + (size_t)(s0 + sl) * EE + e0) = make_float4(o0, o1, o2, o3);
    }
}

// ---------------------------------------------------------------------------
// Row softmax over length-2048 rows; ANGLE variant converts complex scores
// (SR,SI) in-place to cw = softmax(SR) * (SR,SI)/|S|  (i.e. w * exp(i*angle)).
// ---------------------------------------------------------------------------
template<bool ANGLE>
__launch_bounds__(256)
__global__ void softmax_rows(float* __restrict__ SR, float* __restrict__ SI)
{
    const size_t base = (size_t)blockIdx.x * SS_;
    const int tid = threadIdx.x;
    float vr[8], vi[8];
    float m = -3.4e38f;
    #pragma unroll
    for (int j = 0; j < 8; ++j) {
        vr[j] = SR[base + tid + j * 256];
        if (ANGLE) vi[j] = SI[base + tid + j * 256];
        m = fmaxf(m, vr[j]);
    }
    __shared__ float sred[4];
    #pragma unroll
    for (int off = 32; off > 0; off >>= 1) m = fmaxf(m, __shfl_xor(m, off, 64));
    if ((tid & 63) == 0) sred[tid >> 6] = m;
    __syncthreads();
    const float rm = fmaxf(fmaxf(sred[0], sred[1]), fmaxf(sred[2], sred[3]));
    float p[8]; float l = 0.f;
    #pragma unroll
    for (int j = 0; j < 8; ++j) { p[j] = expf(vr[j] - rm); l += p[j]; }
    #pragma unroll
    for (int off = 32; off > 0; off >>= 1) l += __shfl_xor(l, off, 64);
    __syncthreads();
    if ((tid & 63) == 0) sred[tid >> 6] = l;
    __syncthreads();
    const float inv = 1.f / (sred[0] + sred[1] + sred[2] + sred[3]);
    #pragma unroll
    for (int j = 0; j < 8; ++j) {
        float w = p[j] * inv;
        if (ANGLE) {
            float r = sqrtf(vr[j] * vr[j] + vi[j] * vi[j]);
            float cre, cim;
            if (r > 0.f) { float ir = w / r; cre = ir * vr[j]; cim = ir * vi[j]; }
            else { cre = w; cim = 0.f; }
            SR[base + tid + j * 256] = cre;
            SI[base + tid + j * 256] = cim;
        } else {
            SR[base + tid + j * 256] = w;
        }
    }
}

// ---------------------------------------------------------------------------
// MHA over L=3, 16 heads of dim 64. QKV rows: [p][l][0:1024=q,1024:2048=k,2048:3072=v]
// (row pitch 9216). Output AO: (B*S*3, 1024) contiguous.
// ---------------------------------------------------------------------------
__launch_bounds__(256)
__global__ void mha_small(const float* __restrict__ QKV, float* __restrict__ AO)
{
    const int p = blockIdx.x;
    const int tid = threadIdx.x;
    const int h = tid >> 4, i = tid & 15;
    const float* base = QKV + (size_t)p * 9216;
    float4 q[3], k[3], v[3];
    #pragma unroll
    for (int l = 0; l < 3; ++l) {
        const float* row = base + l * 3072 + h * 64 + i * 4;
        q[l] = *(const float4*)(row);
        k[l] = *(const float4*)(row + 1024);
        v[l] = *(const float4*)(row + 2048);
    }
    float sc[3][3];
    #pragma unroll
    for (int l = 0; l < 3; ++l)
        #pragma unroll
        for (int m2 = 0; m2 < 3; ++m2) {
            float d = q[l].x * k[m2].x + q[l].y * k[m2].y + q[l].z * k[m2].z + q[l].w * k[m2].w;
            #pragma unroll
            for (int off = 8; off >= 1; off >>= 1) d += __shfl_xor(d, off, 16);
            sc[l][m2] = d * 0.125f;
        }
    #pragma unroll
    for (int l = 0; l < 3; ++l) {
        float mx = fmaxf(sc[l][0], fmaxf(sc[l][1], sc[l][2]));
        float e0 = expf(sc[l][0] - mx), e1 = expf(sc[l][1] - mx), e2 = expf(sc[l][2] - mx);
        float inv = 1.f / (e0 + e1 + e2);
        float a0 = e0 * inv, a1 = e1 * inv, a2 = e2 * inv;
        float4 ov;
        ov.x = a0 * v[0].x + a1 * v[1].x + a2 * v[2].x;
        ov.y = a0 * v[0].y + a1 * v[1].y + a2 * v[2].y;
        ov.z = a0 * v[0].z + a1 * v[1].z + a2 * v[2].z;
        ov.w = a0 * v[0].w + a1 * v[1].w + a2 * v[2].w;
        *(float4*)(AO + ((size_t)p * 3 + l) * 1024 + h * 64 + i * 4) = ov;
    }
}

// ---------------------------------------------------------------------------
// Host side
// ---------------------------------------------------------------------------
static void gemm(hipStream_t st, bool tb, const float* A, const float* Bsrc, float* C,
                 const float* bias, int M, int N, int K, int lda, int ldb, int ldc,
                 long sA, long sB, long sC, float alpha, float beta, int batch)
{
    dim3 g(N / TN, M / TM, batch), blk(256);
    bool ub = (beta != 0.0f), ubi = (bias != nullptr);
#define GCASE(TB, BE, BI) gemm_kernel<TB, BE, BI><<<g, blk, 0, st>>>(A, Bsrc, C, bias, M, N, K, lda, ldb, ldc, sA, sB, sC, alpha, beta)
    if (tb) {
        if (ub)  { if (ubi) GCASE(true, true, true);  else GCASE(true, true, false); }
        else     { if (ubi) GCASE(true, false, true); else GCASE(true, false, false); }
    } else {
        if (ub)  { if (ubi) GCASE(false, true, true);  else GCASE(false, true, false); }
        else     { if (ubi) GCASE(false, false, true); else GCASE(false, false, false); }
    }
#undef GCASE
}

extern "C" void kernel_launch(void* const* d_in, const int* in_sizes, int n_in,
                              void* d_out, int out_size, void* d_ws, size_t ws_size,
                              hipStream_t stream)
{
    const float* query = (const float*)d_in[0];
    const float* Wp[3] = {(const float*)d_in[1], (const float*)d_in[6],  (const float*)d_in[11]};
    const float* bp[3] = {(const float*)d_in[2], (const float*)d_in[7],  (const float*)d_in[12]};
    const float* Wc[3] = {(const float*)d_in[3], (const float*)d_in[8],  (const float*)d_in[13]};
    const float* bc[3] = {(const float*)d_in[4], (const float*)d_in[9],  (const float*)d_in[14]};
    const float* Fp[3] = {(const float*)d_in[5], (const float*)d_in[10], (const float*)d_in[15]};
    const float* mha_iw = (const float*)d_in[16];
    const float* mha_ib = (const float*)d_in[17];
    const float* mha_ow = (const float*)d_in[18];
    const float* mha_ob = (const float*)d_in[19];
    const float* fus_W  = (const float*)d_in[20];
    const float* fus_b  = (const float*)d_in[21];
    float* out = (float*)d_out;
    float* ws = (float*)d_ws;

    const size_t N  = (size_t)BB * SS_ * EE;       // 4194304 (also = S*S)
    const size_t SE = (size_t)SS_ * EE;            // 2097152
    const size_t SSq = (size_t)SS_ * SS_;          // 4194304

    // ws layout (floats): [MAT0 | MAT1 | P0..P7 | DOM0..2 | FW(3*16K) | WT(3*48K)]
    const size_t need = (13 * N + 3 * (size_t)CC * EE + 3 * (size_t)CC * EE * 3) * sizeof(float);
    if (ws_size < need) return;  // insufficient scratch -> loud validation failure

    float* MAT0 = ws;
    float* MAT1 = ws + N;
    float* P[8];
    for (int i = 0; i < 8; ++i) P[i] = ws + (2 + i) * N;
    float* DOM[3];
    for (int i = 0; i < 3; ++i) DOM[i] = ws + (10 + i) * N;
    float* FW = ws + 13 * N;
    float* WT = FW + 3 * (size_t)CC * EE;
    float* scre = P[5];   // spans P5..P6 (2N)
    float* scim = P[0];   // spans P0..P1 (2N)
    const float scale = 0.03125f;   // 1/sqrt(1024)

    // prep: fw softmax + Wc transposes
    for (int d = 0; d < 3; ++d) {
        softmax_C<<<dim3(EE / 256), dim3(256), 0, stream>>>(Fp[d], FW + (size_t)d * CC * EE);
        transpose_wc<<<dim3((CC * EE * 3 + 255) / 256), dim3(256), 0, stream>>>(Wc[d], WT + (size_t)d * CC * EE * 3);
    }

    // ================= FOURIER =================
    gemm(stream, true, query, Wp[0], P[0], bp[0], BB * SS_, EE, EE, EE, EE, EE, 0, 0, 0, 1.f, 0.f, 1);
    gen_dft<<<dim3((int)(SSq / 256)), dim3(256), 0, stream>>>(MAT0, MAT1);
    // forward DFT: s_re = Ccos@xd, s_im = (-sin)@xd   (batched over B, shared A)
    gemm(stream, false, MAT0, P[0], P[1], nullptr, SS_, EE, SS_, SS_, EE, EE, 0, (long)SE, (long)SE, 1.f, 0.f, BB);
    gemm(stream, false, MAT1, P[0], P[2], nullptr, SS_, EE, SS_, SS_, EE, EE, 0, (long)SE, (long)SE, 1.f, 0.f, BB);
    // conv + channel mix (re, im)
    {
        dim3 g(BB * SS_ / TS_CONV), b(256);
        conv_channels<<<g, b, 0, stream>>>(P[1], WT, bc[0], FW, P[3]);
        conv_channels<<<g, b, 0, stream>>>(P[2], WT, bc[0], FW, P[4]);
    }
    // complex scores (scaled)
    gemm(stream, true, P[3], P[3], scre, nullptr, SS_, SS_, EE, EE, EE, SS_, (long)SE, (long)SE, (long)SSq,  scale, 0.f, BB);
    gemm(stream, true, P[4], P[4], scre, nullptr, SS_, SS_, EE, EE, EE, SS_, (long)SE, (long)SE, (long)SSq, -scale, 1.f, BB);
    gemm(stream, true, P[3], P[4], scim, nullptr, SS_, SS_, EE, EE, EE, SS_, (long)SE, (long)SE, (long)SSq,  scale, 0.f, BB);
    gemm(stream, true, P[4], P[3], scim, nullptr, SS_, SS_, EE, EE, EE, SS_, (long)SE, (long)SE, (long)SSq,  scale, 1.f, BB);
    softmax_rows<true><<<dim3(BB * SS_), dim3(256), 0, stream>>>(scre, scim);
    // out = cw @ v (complex)
    gemm(stream, false, scre, P[3], P[2], nullptr, SS_, EE, SS_, SS_, EE, EE, (long)SSq, (long)SE, (long)SE,  1.f, 0.f, BB);
    gemm(stream, false, scim, P[4], P[2], nullptr, SS_, EE, SS_, SS_, EE, EE, (long)SSq, (long)SE, (long)SE, -1.f, 1.f, BB);
    gemm(stream, false, scre, P[4], P[7], nullptr, SS_, EE, SS_, SS_, EE, EE, (long)SSq, (long)SE, (long)SE,  1.f, 0.f, BB);
    gemm(stream, false, scim, P[3], P[7], nullptr, SS_, EE, SS_, SS_, EE, EE, (long)SSq, (long)SE, (long)SE,  1.f, 1.f, BB);
    // ifft real part: (1/S)(Ccos@Re + (-sin)@Im)
    gemm(stream, false, MAT0, P[2], DOM[0], nullptr, SS_, EE, SS_, SS_, EE, EE, 0, (long)SE, (long)SE, 1.f / SS_, 0.f, BB);
    gemm(stream, false, MAT1, P[7], DOM[0], nullptr, SS_, EE, SS_, SS_, EE, EE, 0, (long)SE, (long)SE, 1.f / SS_, 1.f, BB);

    // ================= WAVELET =================
    gemm(stream, true, query, Wp[1], P[0], bp[1], BB * SS_, EE, EE, EE, EE, EE, 0, 0, 0, 1.f, 0.f, 1);
    for (int l = 0; l <= 10; ++l) {
        int h = 1024 >> l;
        const float* cur = (l == 0) ? P[0] : ((l & 1) ? P[1] : P[0]);
        float* nxt = (l < 10) ? ((l & 1) ? P[0] : P[1]) : P[2];
        size_t tot = (size_t)BB * h * EE;
        haar_level<<<dim3((int)((tot + 255) / 256)), dim3(256), 0, stream>>>(cur, nxt, P[2], h);
    }
    {
        dim3 g(BB * SS_ / TS_CONV), b(256);
        conv_channels<<<g, b, 0, stream>>>(P[2], WT + (size_t)CC * EE * 3, bc[1], FW + (size_t)CC * EE, P[3]);
    }
    gemm(stream, true, P[3], P[3], scre, nullptr, SS_, SS_, EE, EE, EE, SS_, (long)SE, (long)SE, (long)SSq, scale, 0.f, BB);
    softmax_rows<false><<<dim3(BB * SS_), dim3(256), 0, stream>>>(scre, nullptr);
    gemm(stream, false, scre, P[3], DOM[1], nullptr, SS_, EE, SS_, SS_, EE, EE, (long)SSq, (long)SE, (long)SE, 1.f, 0.f, BB);

    // ================= COSINE =================
    gemm(stream, true, query, Wp[2], P[0], bp[2], BB * SS_, EE, EE, EE, EE, EE, 0, 0, 0, 1.f, 0.f, 1);
    gen_dct<<<dim3((int)(SSq / 256)), dim3(256), 0, stream>>>(MAT0, MAT1);
    gemm(stream, false, MAT0, P[0], P[1], nullptr, SS_, EE, SS_, SS_, EE, EE, 0, (long)SE, (long)SE, 1.f, 0.f, BB);
    {
        dim3 g(BB * SS_ / TS_CONV), b(256);
        conv_channels<<<g, b, 0, stream>>>(P[1], WT + 2 * (size_t)CC * EE * 3, bc[2], FW + 2 * (size_t)CC * EE, P[3]);
    }
    gemm(stream, true, P[3], P[3], scre, nullptr, SS_, SS_, EE, EE, EE, SS_, (long)SE, (long)SE, (long)SSq, scale, 0.f, BB);
    softmax_rows<false><<<dim3(BB * SS_), dim3(256), 0, stream>>>(scre, nullptr);
    gemm(stream, false, scre, P[3], P[2], nullptr, SS_, EE, SS_, SS_, EE, EE, (long)SSq, (long)SE, (long)SE, 1.f, 0.f, BB);
    gemm(stream, false, MAT1, P[2], DOM[2], nullptr, SS_, EE, SS_, SS_, EE, EE, 0, (long)SE, (long)SE, 1.f, 0.f, BB);

    // ================= MHA + FUSION =================
    float* QKV  = ws;            // 9N, overlays MAT0/MAT1/P0..P6 (dead)
    float* ATTN = ws + 10 * N;   // 3N, overlays DOM (dead after qkv GEMMs)
    float* CORR = ws;            // 3N, overlays QKV (dead after mha_small)
    for (int l = 0; l < 3; ++l)
        gemm(stream, true, DOM[l], mha_iw, QKV + (size_t)l * 3072, mha_ib,
             BB * SS_, 3 * EE, EE, EE, EE, 3 * 3072, 0, 0, 0, 1.f, 0.f, 1);
    mha_small<<<dim3(BB * SS_), dim3(256), 0, stream>>>(QKV, ATTN);
    gemm(stream, true, ATTN, mha_ow, CORR, mha_ob, BB * SS_ * 3, EE, EE, EE, EE, EE, 0, 0, 0, 1.f, 0.f, 1);
    gemm(stream, true, CORR, fus_W, out, fus_b, BB * SS_, EE, 3 * EE, 3 * EE, 3 * EE, EE, 0, 0, 0, 1.f, 0.f, 1);
}

// Round 2
// 2322.639 us; speedup vs baseline: 2.7974x; 2.7974x over previous
//
#include <hip/hip_runtime.h>
#include <cmath>

// Problem constants
#define BB 2
#define SS_ 2048
#define EE 1024
#define CC 16

typedef __attribute__((ext_vector_type(8))) short short8v;
typedef __attribute__((ext_vector_type(4))) float floatx4;

// ---------------------------------------------------------------------------
// Split-bf16 (bf16x3) MFMA GEMM: C = alpha * A @ B^T [+ beta*C] [+ bias[n]]
// A: (M,K) row-major (lda); Bsrc: (N,K) row-major (ldb)  [always "TRANSB"]
// fp32 emulated via x = hi(bf16,trunc) + lo(bf16,trunc):
//   A.B ~= Ah.Bh + Ah.Bl + Al.Bh    (error ~2^-16 relative per product)
// Tile: 128x128, BK=32, 256 threads = 4 waves of 64x64, mfma_f32_16x16x32_bf16.
// Requires M%128==0, N%128==0, K%32==0.
// ---------------------------------------------------------------------------
#define BM 128
#define BN 128
#define BK 32
#define LDP 40   // LDS row pitch in shorts (pad: 80B rows -> 2-way-only read conflicts)

__device__ __forceinline__ void split4(const float4 v, short4& h, short4& l)
{
    unsigned ux = __float_as_uint(v.x), uy = __float_as_uint(v.y);
    unsigned uz = __float_as_uint(v.z), uw = __float_as_uint(v.w);
    h.x = (short)(ux >> 16); h.y = (short)(uy >> 16);
    h.z = (short)(uz >> 16); h.w = (short)(uw >> 16);
    float lx = v.x - __uint_as_float(ux & 0xFFFF0000u);
    float ly = v.y - __uint_as_float(uy & 0xFFFF0000u);
    float lz = v.z - __uint_as_float(uz & 0xFFFF0000u);
    float lw = v.w - __uint_as_float(uw & 0xFFFF0000u);
    l.x = (short)(__float_as_uint(lx) >> 16);
    l.y = (short)(__float_as_uint(ly) >> 16);
    l.z = (short)(__float_as_uint(lz) >> 16);
    l.w = (short)(__float_as_uint(lw) >> 16);
}

template<bool BETA, bool BIAS>
__launch_bounds__(256, 2)
__global__ void gemm_bf16x3(const float* __restrict__ A, const float* __restrict__ Bsrc,
                            float* __restrict__ C, const float* __restrict__ bias,
                            int K, int lda, int ldb, int ldc,
                            long sA, long sB, long sC, float alpha, float beta)
{
    __shared__ short sAh[BM * LDP], sAl[BM * LDP], sBh[BN * LDP], sBl[BN * LDP];
    const int bz = blockIdx.z;
    A += (size_t)bz * sA; Bsrc += (size_t)bz * sB; C += (size_t)bz * sC;
    const int tid = threadIdx.x;
    const int m0 = blockIdx.y * BM, n0 = blockIdx.x * BN;

    // staging map: thread covers rows (tid>>3)+32c, k-offset (tid&7)*4
    const int lr0 = tid >> 3;
    const int kc0 = (tid & 7) * 4;
    const float* pa = A + (size_t)(m0 + lr0) * lda + kc0;
    const float* pb = Bsrc + (size_t)(n0 + lr0) * ldb + kc0;

    float4 ra[4], rb[4];
    #pragma unroll
    for (int c = 0; c < 4; ++c) {
        ra[c] = *(const float4*)(pa + (size_t)c * 32 * lda);
        rb[c] = *(const float4*)(pb + (size_t)c * 32 * ldb);
    }

    const int lane = tid & 63, wid = tid >> 6;
    const int wm = wid >> 1, wn = wid & 1;
    const int lr = lane & 15, qd = lane >> 4;
    const int arow = wm * 64 + lr;
    const int brow = wn * 64 + lr;
    const int koff = qd * 8;

    floatx4 acc[4][4];
    #pragma unroll
    for (int i = 0; i < 4; ++i)
        #pragma unroll
        for (int j = 0; j < 4; ++j)
            acc[i][j] = (floatx4){0.f, 0.f, 0.f, 0.f};

    for (int kt = 0; kt < K; kt += BK) {
        __syncthreads();   // previous-iteration LDS reads complete
        #pragma unroll
        for (int c = 0; c < 4; ++c) {
            const int row = lr0 + c * 32;
            short4 h, l;
            split4(ra[c], h, l);
            *(short4*)&sAh[row * LDP + kc0] = h;
            *(short4*)&sAl[row * LDP + kc0] = l;
            split4(rb[c], h, l);
            *(short4*)&sBh[row * LDP + kc0] = h;
            *(short4*)&sBl[row * LDP + kc0] = l;
        }
        __syncthreads();
        if (kt + BK < K) {               // prefetch next tile; overlaps MFMA below
            pa += BK; pb += BK;
            #pragma unroll
            for (int c = 0; c < 4; ++c) {
                ra[c] = *(const float4*)(pa + (size_t)c * 32 * lda);
                rb[c] = *(const float4*)(pb + (size_t)c * 32 * ldb);
            }
        }
        short8v ah[4], al[4], bh[4], bl[4];
        #pragma unroll
        for (int i = 0; i < 4; ++i) {
            ah[i] = *(const short8v*)&sAh[(arow + i * 16) * LDP + koff];
            al[i] = *(const short8v*)&sAl[(arow + i * 16) * LDP + koff];
            bh[i] = *(const short8v*)&sBh[(brow + i * 16) * LDP + koff];
            bl[i] = *(const short8v*)&sBl[(brow + i * 16) * LDP + koff];
        }
        #pragma unroll
        for (int i = 0; i < 4; ++i)
            #pragma unroll
            for (int j = 0; j < 4; ++j)
                acc[i][j] = __builtin_amdgcn_mfma_f32_16x16x32_bf16(ah[i], bh[j], acc[i][j], 0, 0, 0);
        #pragma unroll
        for (int i = 0; i < 4; ++i)
            #pragma unroll
            for (int j = 0; j < 4; ++j)
                acc[i][j] = __builtin_amdgcn_mfma_f32_16x16x32_bf16(ah[i], bl[j], acc[i][j], 0, 0, 0);
        #pragma unroll
        for (int i = 0; i < 4; ++i)
            #pragma unroll
            for (int j = 0; j < 4; ++j)
                acc[i][j] = __builtin_amdgcn_mfma_f32_16x16x32_bf16(al[i], bh[j], acc[i][j], 0, 0, 0);
    }

    // epilogue: C/D layout col=lane&15, row=quad*4+reg
    #pragma unroll
    for (int i = 0; i < 4; ++i) {
        const int mbase = m0 + wm * 64 + i * 16 + qd * 4;
        #pragma unroll
        for (int j = 0; j < 4; ++j) {
            const int n = n0 + wn * 64 + j * 16 + lr;
            float bv = 0.f;
            if (BIAS) bv = bias[n];
            #pragma unroll
            for (int r = 0; r < 4; ++r) {
                size_t off = (size_t)(mbase + r) * ldc + n;
                float v = alpha * acc[i][j][r];
                if (BETA) v += beta * C[off];
                if (BIAS) v += bv;
                C[off] = v;
            }
        }
    }
}

// ---------------------------------------------------------------------------
// 32x32 tiled transpose: X (rows,cols) slab -> XT (cols,rows), per-batch z
// ---------------------------------------------------------------------------
__global__ void transpose_k(const float* __restrict__ X, float* __restrict__ XT,
                            int rows, int cols)
{
    __shared__ float tile[32][33];
    const size_t slab = (size_t)rows * cols;
    const float* Xs = X + (size_t)blockIdx.z * slab;
    float* Ts = XT + (size_t)blockIdx.z * slab;
    const int lx = threadIdx.x & 31, ly = threadIdx.x >> 5;
    const int r0 = blockIdx.y * 32, c0 = blockIdx.x * 32;
    #pragma unroll
    for (int p = 0; p < 4; ++p)
        tile[ly + p * 8][lx] = Xs[(size_t)(r0 + ly + p * 8) * cols + c0 + lx];
    __syncthreads();
    #pragma unroll
    for (int p = 0; p < 4; ++p)
        Ts[(size_t)(c0 + ly + p * 8) * rows + r0 + lx] = tile[lx][ly + p * 8];
}

// ---------------------------------------------------------------------------
// DFT twiddle matrices (exact integer angle reduction)
// ---------------------------------------------------------------------------
__global__ void gen_dft(float* __restrict__ Cc, float* __restrict__ Sn)
{
    size_t idx = (size_t)blockIdx.x * 256 + threadIdx.x;
    int k = (int)(idx >> 11);
    int n = (int)(idx & 2047);
    int m = (k * n) & 2047;
    float ang = (float)(6.283185307179586 * (double)m / 2048.0);
    Cc[idx] = cosf(ang);
    Sn[idx] = -sinf(ang);
}

// DCT-II matrices, mimicking the reference's fp32 arithmetic order. I = D^T.
__global__ void gen_dct(float* __restrict__ D, float* __restrict__ I)
{
    size_t idx = (size_t)blockIdx.x * 256 + threadIdx.x;
    int i = (int)(idx >> 11);
    int j = (int)(idx & 2047);
    const float r1 = 0.022097086912079608f;
    const float r2 = 0.03125f;
    const float pif = 3.14159265358979323846f;
    float a  = (pif * (float)i) * (float)(2 * j + 1) / 4096.0f;
    D[idx] = cosf(a) * (i == 0 ? r1 : r2);
    float ai = (pif * (float)j) * (float)(2 * i + 1) / 4096.0f;
    I[idx] = cosf(ai) * (j == 0 ? r1 : r2);
}

__global__ void softmax_C(const float* __restrict__ Fp, float* __restrict__ fw)
{
    int e = blockIdx.x * 256 + threadIdx.x;
    if (e >= EE) return;
    float v[CC]; float m = -3.4e38f;
    #pragma unroll
    for (int c = 0; c < CC; ++c) { v[c] = Fp[c * EE + e]; m = fmaxf(m, v[c]); }
    float s = 0.f;
    #pragma unroll
    for (int c = 0; c < CC; ++c) { v[c] = expf(v[c] - m); s += v[c]; }
    float inv = 1.f / s;
    #pragma unroll
    for (int c = 0; c < CC; ++c) fw[c * EE + e] = v[c] * inv;
}

__global__ void transpose_wc(const float* __restrict__ Wc, float* __restrict__ Wt)
{
    int idx = blockIdx.x * 256 + threadIdx.x;
    if (idx >= CC * EE * 3) return;
    int c = idx / (EE * 3); int rem = idx % (EE * 3); int e = rem / 3; int k = rem % 3;
    Wt[(e * 3 + k) * CC + c] = Wc[idx];
}

__global__ void haar_level(const float* __restrict__ cur, float* __restrict__ nxt,
                           float* __restrict__ det, int h)
{
    size_t idx = (size_t)blockIdx.x * 256 + threadIdx.x;
    size_t tot = (size_t)BB * h * EE;
    if (idx >= tot) return;
    int e = (int)(idx & (EE - 1));
    size_t t = idx >> 10;
    int i = (int)(t % h);
    int b = (int)(t / h);
    const float SQ2 = 1.41421356237309504880f;
    const size_t SEl = (size_t)SS_ * EE;
    const float* cb = cur + (size_t)b * SEl;
    float ev = cb[(size_t)(2 * i) * EE + e];
    float ov = cb[(size_t)(2 * i + 1) * EE + e];
    det[(size_t)b * SEl + (size_t)(h + i) * EE + e] = (ev - ov) / SQ2;
    nxt[(size_t)b * SEl + (size_t)i * EE + e] = (ev + ov) / SQ2;
}

#define TS_CONV 4
__launch_bounds__(256)
__global__ void conv_channels(const float* __restrict__ X, const float* __restrict__ Wt,
                              const float* __restrict__ bc, const float* __restrict__ fw,
                              float* __restrict__ Out)
{
    __shared__ float xl[TS_CONV + 2][1028];
    __shared__ float chs[TS_CONV][CC];
    __shared__ float red[CC][CC];
    const int blk = blockIdx.x;
    const int spb = SS_ / TS_CONV;
    const int b = blk / spb, s0 = (blk % spb) * TS_CONV;
    const int tid = threadIdx.x;
    const size_t SEl = (size_t)SS_ * EE;
    const float* xb = X + (size_t)b * SEl;
    #pragma unroll
    for (int r = 0; r < TS_CONV + 2; ++r) {
        int sr = s0 - 1 + r;
        float4 v = make_float4(0.f, 0.f, 0.f, 0.f);
        if (sr >= 0 && sr < SS_) v = *(const float4*)(xb + (size_t)sr * EE + tid * 4);
        *(float4*)&xl[r][tid * 4] = v;
    }
    __syncthreads();
    const int c = tid & 15, part = tid >> 4;
    float acc[TS_CONV] = {0.f, 0.f, 0.f, 0.f};
    for (int i = 0; i < EE / CC; ++i) {
        int e = part + CC * i;
        float x6[TS_CONV + 2];
        #pragma unroll
        for (int r = 0; r < TS_CONV + 2; ++r) x6[r] = xl[r][e];
        #pragma unroll
        for (int k = 0; k < 3; ++k) {
            float w = Wt[(e * 3 + k) * CC + c];
            #pragma unroll
            for (int sl = 0; sl < TS_CONV; ++sl) acc[sl] += x6[sl + k] * w;
        }
    }
    for (int sl = 0; sl < TS_CONV; ++sl) {
        red[part][c] = acc[sl];
        __syncthreads();
        if (tid < CC) {
            float t = bc[tid];
            #pragma unroll
            for (int p = 0; p < CC; ++p) t += red[p][tid];
            chs[sl][tid] = t;
        }
        __syncthreads();
    }
    for (int sl = 0; sl < TS_CONV; ++sl) {
        const int e0 = tid * 4;
        float o0 = 0.f, o1 = 0.f, o2 = 0.f, o3 = 0.f;
        #pragma unroll
        for (int cc2 = 0; cc2 < CC; ++cc2) {
            float cv = chs[sl][cc2];
            const float* fr = fw + cc2 * EE + e0;
            o0 += cv * fr[0]; o1 += cv * fr[1]; o2 += cv * fr[2]; o3 += cv * fr[3];
        }
        *(float4*)(Out + (size_t)b * SEl + (size_t)(s0 + sl) * EE + e0) = make_float4(o0, o1, o2, o3);
    }
}

template<bool ANGLE>
__launch_bounds__(256)
__global__ void softmax_rows(float* __restrict__ SR, float* __restrict__ SI)
{
    const size_t base = (size_t)blockIdx.x * SS_;
    const int tid = threadIdx.x;
    float vr[8], vi[8];
    float m = -3.4e38f;
    #pragma unroll
    for (int j = 0; j < 8; ++j) {
        vr[j] = SR[base + tid + j * 256];
        if (ANGLE) vi[j] = SI[base + tid + j * 256];
        m = fmaxf(m, vr[j]);
    }
    __shared__ float sred[4];
    #pragma unroll
    for (int off = 32; off > 0; off >>= 1) m = fmaxf(m, __shfl_xor(m, off, 64));
    if ((tid & 63) == 0) sred[tid >> 6] = m;
    __syncthreads();
    const float rm = fmaxf(fmaxf(sred[0], sred[1]), fmaxf(sred[2], sred[3]));
    float p[8]; float l = 0.f;
    #pragma unroll
    for (int j = 0; j < 8; ++j) { p[j] = expf(vr[j] - rm); l += p[j]; }
    #pragma unroll
    for (int off = 32; off > 0; off >>= 1) l += __shfl_xor(l, off, 64);
    __syncthreads();
    if ((tid & 63) == 0) sred[tid >> 6] = l;
    __syncthreads();
    const float inv = 1.f / (sred[0] + sred[1] + sred[2] + sred[3]);
    #pragma unroll
    for (int j = 0; j < 8; ++j) {
        float w = p[j] * inv;
        if (ANGLE) {
            float r = sqrtf(vr[j] * vr[j] + vi[j] * vi[j]);
            float cre, cim;
            if (r > 0.f) { float ir = w / r; cre = ir * vr[j]; cim = ir * vi[j]; }
            else { cre = w; cim = 0.f; }
            SR[base + tid + j * 256] = cre;
            SI[base + tid + j * 256] = cim;
        } else {
            SR[base + tid + j * 256] = w;
        }
    }
}

__launch_bounds__(256)
__global__ void mha_small(const float* __restrict__ QKV, float* __restrict__ AO)
{
    const int p = blockIdx.x;
    const int tid = threadIdx.x;
    const int h = tid >> 4, i = tid & 15;
    const float* base = QKV + (size_t)p * 9216;
    float4 q[3], k[3], v[3];
    #pragma unroll
    for (int l = 0; l < 3; ++l) {
        const float* row = base + l * 3072 + h * 64 + i * 4;
        q[l] = *(const float4*)(row);
        k[l] = *(const float4*)(row + 1024);
        v[l] = *(const float4*)(row + 2048);
    }
    float sc[3][3];
    #pragma unroll
    for (int l = 0; l < 3; ++l)
        #pragma unroll
        for (int m2 = 0; m2 < 3; ++m2) {
            float d = q[l].x * k[m2].x + q[l].y * k[m2].y + q[l].z * k[m2].z + q[l].w * k[m2].w;
            #pragma unroll
            for (int off = 8; off >= 1; off >>= 1) d += __shfl_xor(d, off, 16);
            sc[l][m2] = d * 0.125f;
        }
    #pragma unroll
    for (int l = 0; l < 3; ++l) {
        float mx = fmaxf(sc[l][0], fmaxf(sc[l][1], sc[l][2]));
        float e0 = expf(sc[l][0] - mx), e1 = expf(sc[l][1] - mx), e2 = expf(sc[l][2] - mx);
        float inv = 1.f / (e0 + e1 + e2);
        float a0 = e0 * inv, a1 = e1 * inv, a2 = e2 * inv;
        float4 ov;
        ov.x = a0 * v[0].x + a1 * v[1].x + a2 * v[2].x;
        ov.y = a0 * v[0].y + a1 * v[1].y + a2 * v[2].y;
        ov.z = a0 * v[0].z + a1 * v[1].z + a2 * v[2].z;
        ov.w = a0 * v[0].w + a1 * v[1].w + a2 * v[2].w;
        *(float4*)(AO + ((size_t)p * 3 + l) * 1024 + h * 64 + i * 4) = ov;
    }
}

// ---------------------------------------------------------------------------
// Host side
// ---------------------------------------------------------------------------
static void gemm(hipStream_t st, const float* A, const float* Bsrc, float* C,
                 const float* bias, int M, int N, int K, int lda, int ldb, int ldc,
                 long sA, long sB, long sC, float alpha, float beta, int batch)
{
    dim3 g(N / BN, M / BM, batch), blk(256);
    bool ub = (beta != 0.0f), ubi = (bias != nullptr);
#define GCASE(BE, BI) gemm_bf16x3<BE, BI><<<g, blk, 0, st>>>(A, Bsrc, C, bias, K, lda, ldb, ldc, sA, sB, sC, alpha, beta)
    if (ub)  { if (ubi) GCASE(true, true);  else GCASE(true, false); }
    else     { if (ubi) GCASE(false, true); else GCASE(false, false); }
#undef GCASE
}

static void transpose(hipStream_t st, const float* X, float* XT, int rows, int cols, int batch)
{
    transpose_k<<<dim3(cols / 32, rows / 32, batch), dim3(256), 0, st>>>(X, XT, rows, cols);
}

extern "C" void kernel_launch(void* const* d_in, const int* in_sizes, int n_in,
                              void* d_out, int out_size, void* d_ws, size_t ws_size,
                              hipStream_t stream)
{
    const float* query = (const float*)d_in[0];
    const float* Wp[3] = {(const float*)d_in[1], (const float*)d_in[6],  (const float*)d_in[11]};
    const float* bp[3] = {(const float*)d_in[2], (const float*)d_in[7],  (const float*)d_in[12]};
    const float* Wc[3] = {(const float*)d_in[3], (const float*)d_in[8],  (const float*)d_in[13]};
    const float* bc[3] = {(const float*)d_in[4], (const float*)d_in[9],  (const float*)d_in[14]};
    const float* Fp[3] = {(const float*)d_in[5], (const float*)d_in[10], (const float*)d_in[15]};
    const float* mha_iw = (const float*)d_in[16];
    const float* mha_ib = (const float*)d_in[17];
    const float* mha_ow = (const float*)d_in[18];
    const float* mha_ob = (const float*)d_in[19];
    const float* fus_W  = (const float*)d_in[20];
    const float* fus_b  = (const float*)d_in[21];
    float* out = (float*)d_out;
    float* ws = (float*)d_ws;

    const size_t N   = (size_t)BB * SS_ * EE;      // 4194304 (== S*S)
    const size_t SE  = (size_t)SS_ * EE;           // 2097152
    const size_t SSq = (size_t)SS_ * SS_;          // 4194304
    const int BS = BB * SS_;                       // 4096

    const size_t need = (13 * N + 3 * (size_t)CC * EE + 3 * (size_t)CC * EE * 3) * sizeof(float);
    if (ws_size < need) return;

    float* MAT0 = ws;
    float* MAT1 = ws + N;
    float* P[8];
    for (int i = 0; i < 8; ++i) P[i] = ws + (2 + i) * N;
    float* DOM[3];
    for (int i = 0; i < 3; ++i) DOM[i] = ws + (10 + i) * N;
    float* FW = ws + 13 * N;
    float* WT = FW + 3 * (size_t)CC * EE;
    float* scre = P[5];   // spans P5..P6
    float* scim = P[0];   // spans P0..P1
    const float scale = 0.03125f;   // 1/sqrt(1024)

    for (int d = 0; d < 3; ++d) {
        softmax_C<<<dim3(EE / 256), dim3(256), 0, stream>>>(Fp[d], FW + (size_t)d * CC * EE);
        transpose_wc<<<dim3((CC * EE * 3 + 255) / 256), dim3(256), 0, stream>>>(Wc[d], WT + (size_t)d * CC * EE * 3);
    }

    // ================= FOURIER =================
    gemm(stream, query, Wp[0], P[0], bp[0], BS, EE, EE, EE, EE, EE, 0, 0, 0, 1.f, 0.f, 1);
    gen_dft<<<dim3((int)(SSq / 256)), dim3(256), 0, stream>>>(MAT0, MAT1);
    transpose(stream, P[0], DOM[1], SS_, EE, BB);                 // xd^T  (E,S) per batch
    gemm(stream, MAT0, DOM[1], P[1], nullptr, SS_, EE, SS_, SS_, SS_, EE, 0, (long)SE, (long)SE, 1.f, 0.f, BB);
    gemm(stream, MAT1, DOM[1], P[2], nullptr, SS_, EE, SS_, SS_, SS_, EE, 0, (long)SE, (long)SE, 1.f, 0.f, BB);
    {
        dim3 g(BS / TS_CONV), b(256);
        conv_channels<<<g, b, 0, stream>>>(P[1], WT, bc[0], FW, P[3]);
        conv_channels<<<g, b, 0, stream>>>(P[2], WT, bc[0], FW, P[4]);
    }
    gemm(stream, P[3], P[3], scre, nullptr, SS_, SS_, EE, EE, EE, SS_, (long)SE, (long)SE, (long)SSq,  scale, 0.f, BB);
    gemm(stream, P[4], P[4], scre, nullptr, SS_, SS_, EE, EE, EE, SS_, (long)SE, (long)SE, (long)SSq, -scale, 1.f, BB);
    gemm(stream, P[3], P[4], scim, nullptr, SS_, SS_, EE, EE, EE, SS_, (long)SE, (long)SE, (long)SSq,  scale, 0.f, BB);
    gemm(stream, P[4], P[3], scim, nullptr, SS_, SS_, EE, EE, EE, SS_, (long)SE, (long)SE, (long)SSq,  scale, 1.f, BB);
    softmax_rows<true><<<dim3(BS), dim3(256), 0, stream>>>(scre, scim);
    transpose(stream, P[3], DOM[1], SS_, EE, BB);                 // v_re^T
    transpose(stream, P[4], DOM[2], SS_, EE, BB);                 // v_im^T
    gemm(stream, scre, DOM[1], P[2], nullptr, SS_, EE, SS_, SS_, SS_, EE, (long)SSq, (long)SE, (long)SE,  1.f, 0.f, BB);
    gemm(stream, scim, DOM[2], P[2], nullptr, SS_, EE, SS_, SS_, SS_, EE, (long)SSq, (long)SE, (long)SE, -1.f, 1.f, BB);
    gemm(stream, scre, DOM[2], P[7], nullptr, SS_, EE, SS_, SS_, SS_, EE, (long)SSq, (long)SE, (long)SE,  1.f, 0.f, BB);
    gemm(stream, scim, DOM[1], P[7], nullptr, SS_, EE, SS_, SS_, SS_, EE, (long)SSq, (long)SE, (long)SE,  1.f, 1.f, BB);
    transpose(stream, P[2], DOM[1], SS_, EE, BB);                 // out_re^T
    transpose(stream, P[7], DOM[2], SS_, EE, BB);                 // out_im^T
    gemm(stream, MAT0, DOM[1], DOM[0], nullptr, SS_, EE, SS_, SS_, SS_, EE, 0, (long)SE, (long)SE, 1.f / SS_, 0.f, BB);
    gemm(stream, MAT1, DOM[2], DOM[0], nullptr, SS_, EE, SS_, SS_, SS_, EE, 0, (long)SE, (long)SE, 1.f / SS_, 1.f, BB);

    // ================= WAVELET =================
    gemm(stream, query, Wp[1], P[0], bp[1], BS, EE, EE, EE, EE, EE, 0, 0, 0, 1.f, 0.f, 1);
    for (int l = 0; l <= 10; ++l) {
        int h = 1024 >> l;
        const float* cur = (l == 0) ? P[0] : ((l & 1) ? P[1] : P[0]);
        float* nxt = (l < 10) ? ((l & 1) ? P[0] : P[1]) : P[2];
        size_t tot = (size_t)BB * h * EE;
        haar_level<<<dim3((int)((tot + 255) / 256)), dim3(256), 0, stream>>>(cur, nxt, P[2], h);
    }
    {
        dim3 g(BS / TS_CONV), b(256);
        conv_channels<<<g, b, 0, stream>>>(P[2], WT + (size_t)CC * EE * 3, bc[1], FW + (size_t)CC * EE, P[3]);
    }
    gemm(stream, P[3], P[3], scre, nullptr, SS_, SS_, EE, EE, EE, SS_, (long)SE, (long)SE, (long)SSq, scale, 0.f, BB);
    softmax_rows<false><<<dim3(BS), dim3(256), 0, stream>>>(scre, nullptr);
    transpose(stream, P[3], P[4], SS_, EE, BB);                   // v^T
    gemm(stream, scre, P[4], DOM[1], nullptr, SS_, EE, SS_, SS_, SS_, EE, (long)SSq, (long)SE, (long)SE, 1.f, 0.f, BB);

    // ================= COSINE =================
    gemm(stream, query, Wp[2], P[0], bp[2], BS, EE, EE, EE, EE, EE, 0, 0, 0, 1.f, 0.f, 1);
    gen_dct<<<dim3((int)(SSq / 256)), dim3(256), 0, stream>>>(MAT0, MAT1);
    transpose(stream, P[0], P[1], SS_, EE, BB);                   // xd^T
    gemm(stream, MAT0, P[1], P[2], nullptr, SS_, EE, SS_, SS_, SS_, EE, 0, (long)SE, (long)SE, 1.f, 0.f, BB);
    {
        dim3 g(BS / TS_CONV), b(256);
        conv_channels<<<g, b, 0, stream>>>(P[2], WT + 2 * (size_t)CC * EE * 3, bc[2], FW + 2 * (size_t)CC * EE, P[3]);
    }
    gemm(stream, P[3], P[3], scre, nullptr, SS_, SS_, EE, EE, EE, SS_, (long)SE, (long)SE, (long)SSq, scale, 0.f, BB);
    softmax_rows<false><<<dim3(BS), dim3(256), 0, stream>>>(scre, nullptr);
    transpose(stream, P[3], P[4], SS_, EE, BB);                   // v^T
    gemm(stream, scre, P[4], P[0], nullptr, SS_, EE, SS_, SS_, SS_, EE, (long)SSq, (long)SE, (long)SE, 1.f, 0.f, BB);
    transpose(stream, P[0], P[1], SS_, EE, BB);                   // out^T
    gemm(stream, MAT1, P[1], DOM[2], nullptr, SS_, EE, SS_, SS_, SS_, EE, 0, (long)SE, (long)SE, 1.f, 0.f, BB);

    // ================= MHA + FUSION =================
    float* QKV  = ws;            // 9N, overlays MAT0/MAT1/P0..P6 (dead)
    float* ATTN = ws + 10 * N;   // 3N, overlays DOM (dead after qkv GEMMs)
    float* CORR = ws;            // 3N, overlays QKV (dead after mha_small)
    for (int l = 0; l < 3; ++l)
        gemm(stream, DOM[l], mha_iw, QKV + (size_t)l * 3072, mha_ib,
             BS, 3 * EE, EE, EE, EE, 3 * 3072, 0, 0, 0, 1.f, 0.f, 1);
    mha_small<<<dim3(BS), dim3(256), 0, stream>>>(QKV, ATTN);
    gemm(stream, ATTN, mha_ow, CORR, mha_ob, BS * 3, EE, EE, EE, EE, EE, 0, 0, 0, 1.f, 0.f, 1);
    gemm(stream, CORR, fus_W, out, fus_b, BS, EE, 3 * EE, 3 * EE, 3 * EE, EE, 0, 0, 0, 1.f, 0.f, 1);
}

// Round 3
// 1118.473 us; speedup vs baseline: 5.8092x; 2.0766x over previous
//
#include <hip/hip_runtime.h>
#include <cmath>

#define BB 2
#define SS_ 2048
#define EE 1024
#define CC 16

typedef __attribute__((ext_vector_type(8))) short short8v;
typedef __attribute__((ext_vector_type(4))) float floatx4;

// ---------------------------------------------------------------------------
// Split-bf16 (bf16x3) MFMA GEMM: C = alpha * A @ B^T [+ beta*C] [+ bias[n]]
// A: (M,K) row-major (lda); Bsrc: (N,K) row-major (ldb)
// Tile: 128x128, BK=32, 256 threads = 4 waves of 64x64, mfma_f32_16x16x32_bf16.
// ---------------------------------------------------------------------------
#define BM 128
#define BN 128
#define BK 32
#define LDP 40

__device__ __forceinline__ void split4(const float4 v, short4& h, short4& l)
{
    unsigned ux = __float_as_uint(v.x), uy = __float_as_uint(v.y);
    unsigned uz = __float_as_uint(v.z), uw = __float_as_uint(v.w);
    h.x = (short)(ux >> 16); h.y = (short)(uy >> 16);
    h.z = (short)(uz >> 16); h.w = (short)(uw >> 16);
    float lx = v.x - __uint_as_float(ux & 0xFFFF0000u);
    float ly = v.y - __uint_as_float(uy & 0xFFFF0000u);
    float lz = v.z - __uint_as_float(uz & 0xFFFF0000u);
    float lw = v.w - __uint_as_float(uw & 0xFFFF0000u);
    l.x = (short)(__float_as_uint(lx) >> 16);
    l.y = (short)(__float_as_uint(ly) >> 16);
    l.z = (short)(__float_as_uint(lz) >> 16);
    l.w = (short)(__float_as_uint(lw) >> 16);
}

template<bool BETA, bool BIAS>
__launch_bounds__(256, 2)
__global__ void gemm_bf16x3(const float* __restrict__ A, const float* __restrict__ Bsrc,
                            float* __restrict__ C, const float* __restrict__ bias,
                            int K, int lda, int ldb, int ldc,
                            long sA, long sB, long sC, float alpha, float beta)
{
    __shared__ short sAh[BM * LDP], sAl[BM * LDP], sBh[BN * LDP], sBl[BN * LDP];
    const int bz = blockIdx.z;
    A += (size_t)bz * sA; Bsrc += (size_t)bz * sB; C += (size_t)bz * sC;
    const int tid = threadIdx.x;
    const int m0 = blockIdx.y * BM, n0 = blockIdx.x * BN;

    const int lr0 = tid >> 3;
    const int kc0 = (tid & 7) * 4;
    const float* pa = A + (size_t)(m0 + lr0) * lda + kc0;
    const float* pb = Bsrc + (size_t)(n0 + lr0) * ldb + kc0;

    float4 ra[4], rb[4];
    #pragma unroll
    for (int c = 0; c < 4; ++c) {
        ra[c] = *(const float4*)(pa + (size_t)c * 32 * lda);
        rb[c] = *(const float4*)(pb + (size_t)c * 32 * ldb);
    }

    const int lane = tid & 63, wid = tid >> 6;
    const int wm = wid >> 1, wn = wid & 1;
    const int lr = lane & 15, qd = lane >> 4;
    const int arow = wm * 64 + lr;
    const int brow = wn * 64 + lr;
    const int koff = qd * 8;

    floatx4 acc[4][4];
    #pragma unroll
    for (int i = 0; i < 4; ++i)
        #pragma unroll
        for (int j = 0; j < 4; ++j)
            acc[i][j] = (floatx4){0.f, 0.f, 0.f, 0.f};

    for (int kt = 0; kt < K; kt += BK) {
        __syncthreads();
        #pragma unroll
        for (int c = 0; c < 4; ++c) {
            const int row = lr0 + c * 32;
            short4 h, l;
            split4(ra[c], h, l);
            *(short4*)&sAh[row * LDP + kc0] = h;
            *(short4*)&sAl[row * LDP + kc0] = l;
            split4(rb[c], h, l);
            *(short4*)&sBh[row * LDP + kc0] = h;
            *(short4*)&sBl[row * LDP + kc0] = l;
        }
        __syncthreads();
        if (kt + BK < K) {
            pa += BK; pb += BK;
            #pragma unroll
            for (int c = 0; c < 4; ++c) {
                ra[c] = *(const float4*)(pa + (size_t)c * 32 * lda);
                rb[c] = *(const float4*)(pb + (size_t)c * 32 * ldb);
            }
        }
        short8v ah[4], al[4], bh[4], bl[4];
        #pragma unroll
        for (int i = 0; i < 4; ++i) {
            ah[i] = *(const short8v*)&sAh[(arow + i * 16) * LDP + koff];
            al[i] = *(const short8v*)&sAl[(arow + i * 16) * LDP + koff];
            bh[i] = *(const short8v*)&sBh[(brow + i * 16) * LDP + koff];
            bl[i] = *(const short8v*)&sBl[(brow + i * 16) * LDP + koff];
        }
        #pragma unroll
        for (int i = 0; i < 4; ++i)
            #pragma unroll
            for (int j = 0; j < 4; ++j)
                acc[i][j] = __builtin_amdgcn_mfma_f32_16x16x32_bf16(ah[i], bh[j], acc[i][j], 0, 0, 0);
        #pragma unroll
        for (int i = 0; i < 4; ++i)
            #pragma unroll
            for (int j = 0; j < 4; ++j)
                acc[i][j] = __builtin_amdgcn_mfma_f32_16x16x32_bf16(ah[i], bl[j], acc[i][j], 0, 0, 0);
        #pragma unroll
        for (int i = 0; i < 4; ++i)
            #pragma unroll
            for (int j = 0; j < 4; ++j)
                acc[i][j] = __builtin_amdgcn_mfma_f32_16x16x32_bf16(al[i], bh[j], acc[i][j], 0, 0, 0);
    }

    #pragma unroll
    for (int i = 0; i < 4; ++i) {
        const int mbase = m0 + wm * 64 + i * 16 + qd * 4;
        #pragma unroll
        for (int j = 0; j < 4; ++j) {
            const int n = n0 + wn * 64 + j * 16 + lr;
            float bv = 0.f;
            if (BIAS) bv = bias[n];
            #pragma unroll
            for (int r = 0; r < 4; ++r) {
                size_t off = (size_t)(mbase + r) * ldc + n;
                float v = alpha * acc[i][j][r];
                if (BETA) v += beta * C[off];
                if (BIAS) v += bv;
                C[off] = v;
            }
        }
    }
}

// ---------------------------------------------------------------------------
// Skinny VALU fp32 GEMM: C[M,NT] (+)= alpha * op(A) @ op(B)
//   !TA: A (M,K) row-major.  TA: A (K,M) row-major (used as A^T)
//   !TB: B (K,NT) row-major. TB: B (NT,K) row-major (used as B^T), NT==16 only
// grid: (M/64, 1, Z*KS); ATOMIC => atomicAdd partials (C pre-initialized).
// ---------------------------------------------------------------------------
template<int NT, bool TA, bool TB, bool ATOMIC>
__launch_bounds__(256)
__global__ void skinny(const float* __restrict__ A, const float* __restrict__ Bs,
                       float* __restrict__ C,
                       int K, int lda, int ldb, int ldc,
                       long sA, long sB, long sC, float alpha, int KS)
{
    const int zb = blockIdx.z / KS, ks = blockIdx.z - zb * KS;
    A += (size_t)zb * sA; Bs += (size_t)zb * sB; C += (size_t)zb * sC;
    const int klen = K / KS;
    const int k0 = ks * klen;
    const int m0 = blockIdx.x * 64;
    __shared__ float sa[32][68];
    __shared__ float sb[32][(NT == 48) ? 52 : 20];
    const int tid = threadIdx.x;
    const int tm = tid >> 4, tn = tid & 15;
    constexpr int CN = NT / 16;
    float acc[4][CN] = {};

    for (int kc = k0; kc < k0 + klen; kc += 32) {
        __syncthreads();
        if (!TA) {
            #pragma unroll
            for (int cx = 0; cx < 2; ++cx) {
                int lin = cx * 256 + tid;
                int r = lin >> 3, c4 = (lin & 7) * 4;
                float4 v = *(const float4*)(A + (size_t)(m0 + r) * lda + kc + c4);
                sa[c4 + 0][r] = v.x; sa[c4 + 1][r] = v.y; sa[c4 + 2][r] = v.z; sa[c4 + 3][r] = v.w;
            }
        } else {
            #pragma unroll
            for (int cx = 0; cx < 2; ++cx) {
                int lin = cx * 256 + tid;
                int kk = lin >> 4, c4 = (lin & 15) * 4;
                *(float4*)&sa[kk][c4] = *(const float4*)(A + (size_t)(kc + kk) * lda + m0 + c4);
            }
        }
        if (!TB) {
            constexpr int NF4 = NT / 4;
            for (int lin = tid; lin < 32 * NF4; lin += 256) {
                int kk = lin / NF4, c4 = (lin % NF4) * 4;
                *(float4*)&sb[kk][c4] = *(const float4*)(Bs + (size_t)(kc + kk) * ldb + c4);
            }
        } else {
            for (int lin = tid; lin < 128; lin += 256) {
                int n = lin >> 3, c4 = (lin & 7) * 4;
                float4 v = *(const float4*)(Bs + (size_t)n * ldb + kc + c4);
                sb[c4 + 0][n] = v.x; sb[c4 + 1][n] = v.y; sb[c4 + 2][n] = v.z; sb[c4 + 3][n] = v.w;
            }
        }
        __syncthreads();
        #pragma unroll
        for (int kk = 0; kk < 32; ++kk) {
            float4 av = *(const float4*)&sa[kk][tm * 4];
            #pragma unroll
            for (int c = 0; c < CN; ++c) {
                float bv = sb[kk][tn * CN + c];
                acc[0][c] = fmaf(av.x, bv, acc[0][c]);
                acc[1][c] = fmaf(av.y, bv, acc[1][c]);
                acc[2][c] = fmaf(av.z, bv, acc[2][c]);
                acc[3][c] = fmaf(av.w, bv, acc[3][c]);
            }
        }
    }
    #pragma unroll
    for (int r = 0; r < 4; ++r)
        #pragma unroll
        for (int c = 0; c < CN; ++c) {
            int m = m0 + tm * 4 + r, n = tn * CN + c;
            float v = alpha * acc[r][c];
            if (ATOMIC) atomicAdd(&C[(size_t)m * ldc + n], v);
            else C[(size_t)m * ldc + n] = v;
        }
}

// ---------------------------------------------------------------------------
// Trig matrices
// ---------------------------------------------------------------------------
__global__ void gen_dft(float* __restrict__ Cc, float* __restrict__ Sn)
{
    size_t idx = (size_t)blockIdx.x * 256 + threadIdx.x;
    int k = (int)(idx >> 11);
    int n = (int)(idx & 2047);
    int m = (k * n) & 2047;
    float ang = (float)(6.283185307179586 * (double)m / 2048.0);
    Cc[idx] = cosf(ang);
    Sn[idx] = -sinf(ang);
}

__global__ void gen_dct(float* __restrict__ D, float* __restrict__ I)
{
    size_t idx = (size_t)blockIdx.x * 256 + threadIdx.x;
    int i = (int)(idx >> 11);
    int j = (int)(idx & 2047);
    const float r1 = 0.022097086912079608f;
    const float r2 = 0.03125f;
    const float pif = 3.14159265358979323846f;
    float a  = (pif * (float)i) * (float)(2 * j + 1) / 4096.0f;
    D[idx] = cosf(a) * (i == 0 ? r1 : r2);
    float ai = (pif * (float)j) * (float)(2 * i + 1) / 4096.0f;
    I[idx] = cosf(ai) * (j == 0 ? r1 : r2);
}

// ---------------------------------------------------------------------------
// Small prep kernels
// ---------------------------------------------------------------------------
__global__ void softmax_C3(const float* __restrict__ F0, const float* __restrict__ F1,
                           const float* __restrict__ F2, float* __restrict__ fw)
{
    int e = blockIdx.x * 256 + threadIdx.x;
    if (e >= EE) return;
    const float* Fp = blockIdx.y == 0 ? F0 : (blockIdx.y == 1 ? F1 : F2);
    float* out = fw + blockIdx.y * CC * EE;
    float v[CC]; float m = -3.4e38f;
    #pragma unroll
    for (int c = 0; c < CC; ++c) { v[c] = Fp[c * EE + e]; m = fmaxf(m, v[c]); }
    float s = 0.f;
    #pragma unroll
    for (int c = 0; c < CC; ++c) { v[c] = expf(v[c] - m); s += v[c]; }
    float inv = 1.f / s;
    #pragma unroll
    for (int c = 0; c < CC; ++c) out[c * EE + e] = v[c] * inv;
}

__global__ void build_w2(const float* __restrict__ W0, const float* __restrict__ W1,
                         const float* __restrict__ W2_, float* __restrict__ W2cat)
{
    int idx = blockIdx.x * 256 + threadIdx.x;
    if (idx >= 3 * CC * EE * 3) return;
    int d = idx / 49152, r = idx % 49152;
    const float* Wc = d == 0 ? W0 : (d == 1 ? W1 : W2_);
    int c = r / 3072, e = (r % 3072) / 3, k = r % 3;
    W2cat[d * 49152 + e * 48 + c * 3 + k] = Wc[r];
}

__global__ void build_ub(const float* __restrict__ b0, const float* __restrict__ b1,
                         const float* __restrict__ b2, const float* __restrict__ W2cat,
                         float* __restrict__ ub)
{
    int t = threadIdx.x;
    if (t >= 144) return;
    int d = t / 48, c = t % 48;
    const float* bp = d == 0 ? b0 : (d == 1 ? b1 : b2);
    float s = 0.f;
    for (int e = 0; e < EE; ++e) s += bp[e] * W2cat[d * 49152 + e * 48 + c];
    ub[t] = s;
}

// G_d = (1/32) * fw_d @ fw_d^T  (scale folded)
__global__ void build_G(const float* __restrict__ fw, float* __restrict__ G)
{
    int d = blockIdx.x;
    __shared__ float sf[CC * EE];
    for (int lin = threadIdx.x; lin < 4096; lin += 256)
        *(float4*)&sf[lin * 4] = *(const float4*)(fw + d * CC * EE + lin * 4);
    __syncthreads();
    int a = threadIdx.x >> 4, b = threadIdx.x & 15;
    const float4* pa = (const float4*)&sf[a * EE];
    const float4* pb = (const float4*)&sf[b * EE];
    float s = 0.f;
    for (int i = 0; i < 256; ++i) {
        float4 x = pa[i], y = pb[i];
        s += x.x * y.x + x.y * y.y + x.z * y.z + x.w * y.w;
    }
    G[d * 256 + a * 16 + b] = s * 0.03125f;
}

// init: [W3cat zeros | Ucat = ub broadcast | Tfr,Tfi,Tc,Rf,Rc zeros]
__global__ void init_bufs(float* __restrict__ base, const float* __restrict__ ub)
{
    size_t idx = (size_t)blockIdx.x * 256 + threadIdx.x;
    const size_t W3N = 147456, UN = 589824, ZN = 720896;
    if (idx >= W3N + UN + ZN) return;
    float v = 0.f;
    if (idx >= W3N && idx < W3N + UN) {
        size_t r = idx - W3N;
        int d = (int)(r / 196608), c = (int)(r % 48);
        v = ub[d * 48 + c];
    }
    base[idx] = v;
}

__global__ void ib_append(const float* __restrict__ ib, float* __restrict__ Pt)
{
    int idx = blockIdx.x * 256 + threadIdx.x;
    if (idx >= 9216) return;
    int d = idx / 3072, j = idx % 3072;
    Pt[d * 52224 + j * 17 + 16] = ib[j];
}

// Mten[h][l][m][a][b] = 0.125 * sum_d Pt_l[h64+d][a] * Pt_m[1024+h64+d][b]
__launch_bounds__(256)
__global__ void build_M(const float* __restrict__ Pt, float* __restrict__ Mten)
{
    int blk = blockIdx.x;             // h*9 + l*3 + m
    int h = blk / 9, lm = blk % 9;
    int l = lm / 3, m = lm % 3;
    __shared__ float sQ[64][17], sK[64][17];
    for (int lin = threadIdx.x; lin < 1088; lin += 256) {
        int d = lin / 17, a = lin % 17;
        sQ[d][a] = Pt[l * 52224 + (size_t)(h * 64 + d) * 17 + a];
        sK[d][a] = Pt[m * 52224 + (size_t)(1024 + h * 64 + d) * 17 + a];
    }
    __syncthreads();
    for (int o = threadIdx.x; o < 289; o += 256) {
        int a = o / 17, b = o % 17;
        float s = 0.f;
        for (int d = 0; d < 64; ++d) s += sQ[d][a] * sK[d][b];
        Mten[(size_t)blk * 289 + o] = 0.125f * s;
    }
}

__global__ void build_yb(const float* __restrict__ ob, const float* __restrict__ fus_W,
                         const float* __restrict__ fus_b, float* __restrict__ yb)
{
    int n = blockIdx.x * 256 + threadIdx.x;
    if (n >= EE) return;
    float s = fus_b[n];
    for (int j = 0; j < 3072; ++j) s += ob[j & 1023] * fus_W[(size_t)n * 3072 + j];
    yb[n] = s;
}

__global__ void transpose_k(const float* __restrict__ X, float* __restrict__ XT,
                            int rows, int cols)
{
    __shared__ float tile[32][33];
    const int lx = threadIdx.x & 31, ly = threadIdx.x >> 5;
    const int r0 = blockIdx.y * 32, c0 = blockIdx.x * 32;
    #pragma unroll
    for (int p = 0; p < 4; ++p)
        tile[ly + p * 8][lx] = X[(size_t)(r0 + ly + p * 8) * cols + c0 + lx];
    __syncthreads();
    #pragma unroll
    for (int p = 0; p < 4; ++p)
        XT[(size_t)(c0 + ly + p * 8) * rows + r0 + lx] = tile[lx][ly + p * 8];
}

// ---------------------------------------------------------------------------
// Haar level on width-48 buffers
// ---------------------------------------------------------------------------
__global__ void haar48(const float* __restrict__ cur, float* __restrict__ nxt,
                       float* __restrict__ det, int h)
{
    int idx = blockIdx.x * 256 + threadIdx.x;
    int tot = BB * h * 48;
    if (idx >= tot) return;
    int e = idx % 48;
    int t = idx / 48;
    int i = t % h, b = t / h;
    const float SQ2 = 1.41421356237309504880f;
    const float* cb = cur + (size_t)b * 2048 * 48;
    float ev = cb[(size_t)(2 * i) * 48 + e];
    float ov = cb[(size_t)(2 * i + 1) * 48 + e];
    det[(size_t)b * 2048 * 48 + (size_t)(h + i) * 48 + e] = (ev - ov) / SQ2;
    nxt[(size_t)b * 2048 * 48 + (size_t)i * 48 + e] = (ev + ov) / SQ2;
}

// ---------------------------------------------------------------------------
// conv collapse + G fold: T (B,S,48) -> ch (B,S,16), Qp = ch@G (scaled)
// ---------------------------------------------------------------------------
template<bool CPLX>
__launch_bounds__(256)
__global__ void conv_mix(const float* __restrict__ Tre, const float* __restrict__ Tim,
                         const float* __restrict__ G, const float* __restrict__ bc,
                         float* __restrict__ chR, float* __restrict__ chI,
                         float* __restrict__ QR, float* __restrict__ QI)
{
    const int s0 = blockIdx.x * 256, b = blockIdx.y;
    const int tid = threadIdx.x;
    __shared__ float sR[258 * 49];
    __shared__ float sI[CPLX ? 258 * 49 : 1];
    __shared__ float sG[256];
    if (tid < 256) sG[tid] = G[tid];
    for (int lin = tid; lin < 258 * 12; lin += 256) {
        int r = lin / 12, c4 = (lin % 12) * 4;
        int srow = s0 - 1 + r;
        float4 v = {0.f, 0.f, 0.f, 0.f}, w = {0.f, 0.f, 0.f, 0.f};
        if (srow >= 0 && srow < 2048) {
            v = *(const float4*)(Tre + ((size_t)(b * 2048 + srow)) * 48 + c4);
            if (CPLX) w = *(const float4*)(Tim + ((size_t)(b * 2048 + srow)) * 48 + c4);
        }
        sR[r * 49 + c4] = v.x; sR[r * 49 + c4 + 1] = v.y;
        sR[r * 49 + c4 + 2] = v.z; sR[r * 49 + c4 + 3] = v.w;
        if (CPLX) {
            sI[r * 49 + c4] = w.x; sI[r * 49 + c4 + 1] = w.y;
            sI[r * 49 + c4 + 2] = w.z; sI[r * 49 + c4 + 3] = w.w;
        }
    }
    __syncthreads();
    float ch[16], chi[16];
    #pragma unroll
    for (int c = 0; c < 16; ++c) {
        float bcv = bc[c];
        ch[c] = sR[tid * 49 + 3 * c] + sR[(tid + 1) * 49 + 3 * c + 1]
              + sR[(tid + 2) * 49 + 3 * c + 2] + bcv;
        if (CPLX)
            chi[c] = sI[tid * 49 + 3 * c] + sI[(tid + 1) * 49 + 3 * c + 1]
                   + sI[(tid + 2) * 49 + 3 * c + 2] + bcv;
    }
    size_t ro = ((size_t)(b * 2048 + s0 + tid)) * 16;
    #pragma unroll
    for (int j = 0; j < 4; ++j) *(float4*)(chR + ro + j * 4) = *(float4*)&ch[j * 4];
    if (CPLX)
        #pragma unroll
        for (int j = 0; j < 4; ++j) *(float4*)(chI + ro + j * 4) = *(float4*)&chi[j * 4];
    float qp[16], qpi[16];
    #pragma unroll
    for (int cc = 0; cc < 16; ++cc) {
        float t = 0.f, ti = 0.f;
        #pragma unroll
        for (int c = 0; c < 16; ++c) {
            float g = sG[c * 16 + cc];
            t = fmaf(ch[c], g, t);
            if (CPLX) ti = fmaf(chi[c], g, ti);
        }
        qp[cc] = t;
        if (CPLX) qpi[cc] = ti;
    }
    #pragma unroll
    for (int j = 0; j < 4; ++j) *(float4*)(QR + ro + j * 4) = *(float4*)&qp[j * 4];
    if (CPLX)
        #pragma unroll
        for (int j = 0; j < 4; ++j) *(float4*)(QI + ro + j * 4) = *(float4*)&qpi[j * 4];
}

// ---------------------------------------------------------------------------
// Flash attention, rank-16, real: O = softmax(Qp @ ch^T) @ ch
// grid (S/16, B), block 256 = 16 rows x 16 t-lanes
// ---------------------------------------------------------------------------
__launch_bounds__(256)
__global__ void flash_r(const float* __restrict__ Qp, const float* __restrict__ ch,
                        float* __restrict__ O)
{
    const int b = blockIdx.y, s0 = blockIdx.x * 16;
    const int tid = threadIdx.x;
    const int row = tid >> 4, tl = tid & 15;
    __shared__ float sQ[16 * 20];
    __shared__ float sK[128 * 20];
    if (tid < 64) {
        int r = tid >> 2, c4 = (tid & 3) * 4;
        float4 v = *(const float4*)(Qp + ((size_t)(b * 2048 + s0 + r)) * 16 + c4);
        sQ[r * 20 + c4] = v.x; sQ[r * 20 + c4 + 1] = v.y;
        sQ[r * 20 + c4 + 2] = v.z; sQ[r * 20 + c4 + 3] = v.w;
    }
    __syncthreads();
    float q[16];
    #pragma unroll
    for (int e = 0; e < 16; ++e) q[e] = sQ[row * 20 + e];
    float m = -3.4e38f, l = 0.f;
    float acc[16] = {};
    for (int t0 = 0; t0 < 2048; t0 += 128) {
        __syncthreads();
        #pragma unroll
        for (int cx = 0; cx < 2; ++cx) {
            int lin = cx * 256 + tid;
            int r = lin >> 2, c4 = (lin & 3) * 4;
            float4 v = *(const float4*)(ch + ((size_t)(b * 2048 + t0 + r)) * 16 + c4);
            sK[r * 20 + c4] = v.x; sK[r * 20 + c4 + 1] = v.y;
            sK[r * 20 + c4 + 2] = v.z; sK[r * 20 + c4 + 3] = v.w;
        }
        __syncthreads();
        #pragma unroll
        for (int st = 0; st < 8; ++st) {
            const float* kp = &sK[(st * 16 + tl) * 20];
            float kv[16];
            *(float4*)&kv[0] = *(const float4*)kp;
            *(float4*)&kv[4] = *(const float4*)(kp + 4);
            *(float4*)&kv[8] = *(const float4*)(kp + 8);
            *(float4*)&kv[12] = *(const float4*)(kp + 12);
            float s = 0.f;
            #pragma unroll
            for (int e = 0; e < 16; ++e) s = fmaf(q[e], kv[e], s);
            if (s > m) {
                float r2 = expf(m - s);
                l = l * r2 + 1.f;
                #pragma unroll
                for (int e = 0; e < 16; ++e) acc[e] = fmaf(acc[e], r2, kv[e]);
                m = s;
            } else {
                float p = expf(s - m);
                l += p;
                #pragma unroll
                for (int e = 0; e < 16; ++e) acc[e] = fmaf(p, kv[e], acc[e]);
            }
        }
    }
    #pragma unroll
    for (int off = 1; off < 16; off <<= 1) {
        float m2 = __shfl_xor(m, off, 16);
        float l2 = __shfl_xor(l, off, 16);
        float mn = fmaxf(m, m2);
        float ra = expf(m - mn), rb = expf(m2 - mn);
        l = l * ra + l2 * rb;
        #pragma unroll
        for (int e = 0; e < 16; ++e) {
            float a2 = __shfl_xor(acc[e], off, 16);
            acc[e] = acc[e] * ra + a2 * rb;
        }
        m = mn;
    }
    if (tl < 4) {
        float inv = 1.f / l;
        float4 o4 = {acc[tl * 4] * inv, acc[tl * 4 + 1] * inv,
                     acc[tl * 4 + 2] * inv, acc[tl * 4 + 3] * inv};
        *(float4*)(O + ((size_t)(b * 2048 + s0 + row)) * 16 + tl * 4) = o4;
    }
}

// Complex flash: w = softmax(Re(s)); cw = w * s/|s|; O = cw @ (chR + i chI)
__launch_bounds__(256)
__global__ void flash_c(const float* __restrict__ QpR, const float* __restrict__ QpI,
                        const float* __restrict__ chR, const float* __restrict__ chI,
                        float* __restrict__ OR_, float* __restrict__ OI_)
{
    const int b = blockIdx.y, s0 = blockIdx.x * 16;
    const int tid = threadIdx.x;
    const int row = tid >> 4, tl = tid & 15;
    __shared__ float sQR[16 * 20], sQI[16 * 20];
    __shared__ float sKR[128 * 20], sKI[128 * 20];
    if (tid < 64) {
        int r = tid >> 2, c4 = (tid & 3) * 4;
        float4 v = *(const float4*)(QpR + ((size_t)(b * 2048 + s0 + r)) * 16 + c4);
        float4 w = *(const float4*)(QpI + ((size_t)(b * 2048 + s0 + r)) * 16 + c4);
        sQR[r * 20 + c4] = v.x; sQR[r * 20 + c4 + 1] = v.y; sQR[r * 20 + c4 + 2] = v.z; sQR[r * 20 + c4 + 3] = v.w;
        sQI[r * 20 + c4] = w.x; sQI[r * 20 + c4 + 1] = w.y; sQI[r * 20 + c4 + 2] = w.z; sQI[r * 20 + c4 + 3] = w.w;
    }
    __syncthreads();
    float qr[16], qi[16];
    #pragma unroll
    for (int e = 0; e < 16; ++e) { qr[e] = sQR[row * 20 + e]; qi[e] = sQI[row * 20 + e]; }
    float m = -3.4e38f, l = 0.f;
    float aR[16] = {}, aI[16] = {};
    for (int t0 = 0; t0 < 2048; t0 += 128) {
        __syncthreads();
        #pragma unroll
        for (int cx = 0; cx < 2; ++cx) {
            int lin = cx * 256 + tid;
            int r = lin >> 2, c4 = (lin & 3) * 4;
            float4 v = *(const float4*)(chR + ((size_t)(b * 2048 + t0 + r)) * 16 + c4);
            float4 w = *(const float4*)(chI + ((size_t)(b * 2048 + t0 + r)) * 16 + c4);
            sKR[r * 20 + c4] = v.x; sKR[r * 20 + c4 + 1] = v.y; sKR[r * 20 + c4 + 2] = v.z; sKR[r * 20 + c4 + 3] = v.w;
            sKI[r * 20 + c4] = w.x; sKI[r * 20 + c4 + 1] = w.y; sKI[r * 20 + c4 + 2] = w.z; sKI[r * 20 + c4 + 3] = w.w;
        }
        __syncthreads();
        #pragma unroll
        for (int st = 0; st < 8; ++st) {
            const float* kpr = &sKR[(st * 16 + tl) * 20];
            const float* kpi = &sKI[(st * 16 + tl) * 20];
            float kr[16], ki[16];
            *(float4*)&kr[0] = *(const float4*)kpr;     *(float4*)&kr[4] = *(const float4*)(kpr + 4);
            *(float4*)&kr[8] = *(const float4*)(kpr + 8); *(float4*)&kr[12] = *(const float4*)(kpr + 12);
            *(float4*)&ki[0] = *(const float4*)kpi;     *(float4*)&ki[4] = *(const float4*)(kpi + 4);
            *(float4*)&ki[8] = *(const float4*)(kpi + 8); *(float4*)&ki[12] = *(const float4*)(kpi + 12);
            float sre = 0.f, sim = 0.f;
            #pragma unroll
            for (int e = 0; e < 16; ++e) {
                sre = fmaf(qr[e], kr[e], sre); sre = fmaf(-qi[e], ki[e], sre);
                sim = fmaf(qr[e], ki[e], sim); sim = fmaf(qi[e], kr[e], sim);
            }
            float p;
            if (sre > m) {
                float r2 = expf(m - sre);
                l = l * r2 + 1.f;
                #pragma unroll
                for (int e = 0; e < 16; ++e) { aR[e] *= r2; aI[e] *= r2; }
                m = sre;
                p = 1.f;
            } else {
                p = expf(sre - m);
                l += p;
            }
            float rr = sqrtf(sre * sre + sim * sim);
            float wr, wi;
            if (rr > 0.f) { float iv = p / rr; wr = iv * sre; wi = iv * sim; }
            else { wr = p; wi = 0.f; }
            #pragma unroll
            for (int e = 0; e < 16; ++e) {
                aR[e] = fmaf(wr, kr[e], aR[e]); aR[e] = fmaf(-wi, ki[e], aR[e]);
                aI[e] = fmaf(wr, ki[e], aI[e]); aI[e] = fmaf(wi, kr[e], aI[e]);
            }
        }
    }
    #pragma unroll
    for (int off = 1; off < 16; off <<= 1) {
        float m2 = __shfl_xor(m, off, 16);
        float l2 = __shfl_xor(l, off, 16);
        float mn = fmaxf(m, m2);
        float ra = expf(m - mn), rb = expf(m2 - mn);
        l = l * ra + l2 * rb;
        #pragma unroll
        for (int e = 0; e < 16; ++e) {
            float a2 = __shfl_xor(aR[e], off, 16);
            aR[e] = aR[e] * ra + a2 * rb;
            float b2 = __shfl_xor(aI[e], off, 16);
            aI[e] = aI[e] * ra + b2 * rb;
        }
        m = mn;
    }
    float inv = 1.f / l;
    size_t ro = ((size_t)(b * 2048 + s0 + row)) * 16;
    if (tl < 4) {
        float4 o4 = {aR[tl * 4] * inv, aR[tl * 4 + 1] * inv, aR[tl * 4 + 2] * inv, aR[tl * 4 + 3] * inv};
        *(float4*)(OR_ + ro + tl * 4) = o4;
    } else if (tl < 8) {
        int j = tl - 4;
        float4 o4 = {aI[j * 4] * inv, aI[j * 4 + 1] * inv, aI[j * 4 + 2] * inv, aI[j * 4 + 3] * inv};
        *(float4*)(OI_ + ro + j * 4) = o4;
    }
}

// ---------------------------------------------------------------------------
// MHA over L=3 via rank-17 bilinear forms; writes o-features MO (4096, 3*1024)
// grid (4096/256, 16 heads)
// ---------------------------------------------------------------------------
__launch_bounds__(256)
__global__ void mha_o(const float* __restrict__ R0, const float* __restrict__ R1,
                      const float* __restrict__ R2, const float* __restrict__ Pt,
                      const float* __restrict__ Mten, float* __restrict__ MO)
{
    const int tid = threadIdx.x;
    const int p = blockIdx.x * 256 + tid;
    const int h = blockIdx.y;
    __shared__ float sPv[3 * 64 * 20];   // [m][row][a], pitch 20
    __shared__ float sM[9 * 17 * 20];    // [lm][a][b], pitch 20
    for (int lin = tid; lin < 3264; lin += 256) {
        int mm = lin / 1088, rem = lin % 1088;
        int rr = rem / 17, a = rem % 17;
        sPv[(mm * 64 + rr) * 20 + a] = Pt[mm * 52224 + (size_t)(2048 + h * 64 + rr) * 17 + a];
    }
    for (int lin = tid; lin < 2601; lin += 256) {
        int lm = lin / 289, rem = lin % 289;
        int a = rem / 17, bq = rem % 17;
        sM[lm * 340 + a * 20 + bq] = Mten[(size_t)h * 2601 + lin];
    }
    __syncthreads();
    float R[3][16];
    #pragma unroll
    for (int j = 0; j < 4; ++j) {
        *(float4*)&R[0][j * 4] = *(const float4*)(R0 + (size_t)p * 16 + j * 4);
        *(float4*)&R[1][j * 4] = *(const float4*)(R1 + (size_t)p * 16 + j * 4);
        *(float4*)&R[2][j * 4] = *(const float4*)(R2 + (size_t)p * 16 + j * 4);
    }
    float w[3][3];
    #pragma unroll
    for (int l = 0; l < 3; ++l) {
        float sc[3];
        #pragma unroll
        for (int mm = 0; mm < 3; ++mm) {
            const float* Mp = &sM[(l * 3 + mm) * 340];
            float s = 0.f;
            #pragma unroll
            for (int a = 0; a < 17; ++a) {
                const float* mr = Mp + a * 20;
                float t = mr[16];
                #pragma unroll
                for (int bq = 0; bq < 16; ++bq) t = fmaf(mr[bq], R[mm][bq], t);
                float ra = (a < 16) ? R[l][a] : 1.f;
                s = fmaf(ra, t, s);
            }
            sc[mm] = s;
        }
        float mx = fmaxf(sc[0], fmaxf(sc[1], sc[2]));
        float e0 = expf(sc[0] - mx), e1 = expf(sc[1] - mx), e2 = expf(sc[2] - mx);
        float inv = 1.f / (e0 + e1 + e2);
        w[l][0] = e0 * inv; w[l][1] = e1 * inv; w[l][2] = e2 * inv;
    }
    #pragma unroll
    for (int d4 = 0; d4 < 16; ++d4) {
        float4 vm[3];
        #pragma unroll
        for (int mm = 0; mm < 3; ++mm) {
            float vx[4];
            #pragma unroll
            for (int r = 0; r < 4; ++r) {
                const float* pv = &sPv[(mm * 64 + d4 * 4 + r) * 20];
                float t = pv[16];
                #pragma unroll
                for (int a = 0; a < 16; ++a) t = fmaf(R[mm][a], pv[a], t);
                vx[r] = t;
            }
            vm[mm] = (float4){vx[0], vx[1], vx[2], vx[3]};
        }
        #pragma unroll
        for (int l = 0; l < 3; ++l) {
            float4 o4;
            o4.x = w[l][0] * vm[0].x + w[l][1] * vm[1].x + w[l][2] * vm[2].x;
            o4.y = w[l][0] * vm[0].y + w[l][1] * vm[1].y + w[l][2] * vm[2].y;
            o4.z = w[l][0] * vm[0].z + w[l][1] * vm[1].z + w[l][2] * vm[2].z;
            o4.w = w[l][0] * vm[0].w + w[l][1] * vm[1].w + w[l][2] * vm[2].w;
            *(float4*)(MO + (size_t)p * 3072 + l * 1024 + h * 64 + d4 * 4) = o4;
        }
    }
}

// ---------------------------------------------------------------------------
// Host
// ---------------------------------------------------------------------------
static void gemm(hipStream_t st, const float* A, const float* Bsrc, float* C,
                 const float* bias, int M, int N, int K, int lda, int ldb, int ldc,
                 long sA, long sB, long sC, float alpha, float beta, int batch)
{
    dim3 g(N / BN, M / BM, batch), blk(256);
    bool ub = (beta != 0.0f), ubi = (bias != nullptr);
#define GCASE(BE, BI) gemm_bf16x3<BE, BI><<<g, blk, 0, st>>>(A, Bsrc, C, bias, K, lda, ldb, ldc, sA, sB, sC, alpha, beta)
    if (ub)  { if (ubi) GCASE(true, true);  else GCASE(true, false); }
    else     { if (ubi) GCASE(false, true); else GCASE(false, false); }
#undef GCASE
}

extern "C" void kernel_launch(void* const* d_in, const int* in_sizes, int n_in,
                              void* d_out, int out_size, void* d_ws, size_t ws_size,
                              hipStream_t stream)
{
    const float* query = (const float*)d_in[0];
    const float* Wp[3] = {(const float*)d_in[1], (const float*)d_in[6],  (const float*)d_in[11]};
    const float* bp[3] = {(const float*)d_in[2], (const float*)d_in[7],  (const float*)d_in[12]};
    const float* Wc[3] = {(const float*)d_in[3], (const float*)d_in[8],  (const float*)d_in[13]};
    const float* bc[3] = {(const float*)d_in[4], (const float*)d_in[9],  (const float*)d_in[14]};
    const float* Fp[3] = {(const float*)d_in[5], (const float*)d_in[10], (const float*)d_in[15]};
    const float* mha_iw = (const float*)d_in[16];
    const float* mha_ib = (const float*)d_in[17];
    const float* mha_ow = (const float*)d_in[18];
    const float* mha_ob = (const float*)d_in[19];
    const float* fus_W  = (const float*)d_in[20];
    const float* fus_b  = (const float*)d_in[21];
    float* out = (float*)d_out;
    float* ws = (float*)d_ws;

    size_t off = 0;
    auto alloc = [&](size_t n) { float* p = ws + off; off += n; return p; };
    float* MAT0 = alloc(4194304);
    float* MAT1 = alloc(4194304);
    float* DCTD = alloc(4194304);
    float* DCTI = alloc(4194304);
    float* MO   = alloc((size_t)4096 * 3072);
    float* FTb  = alloc((size_t)1024 * 3072);
    float* OWT  = alloc((size_t)1024 * 1024);
    float* fw   = alloc(3 * 16 * 1024);
    float* W2cat = alloc(147456);
    float* ubv  = alloc(256);
    float* Gm   = alloc(1024);
    float* W3cat = alloc(147456);     // init region start
    float* Ucat = alloc(589824);
    float* Tfr  = alloc(196608);
    float* Tfi  = alloc(196608);
    float* Tc   = alloc(196608);
    float* Rf   = alloc(65536);
    float* Rc   = alloc(65536);       // init region end
    float* Tw   = alloc(196608);
    float* HP0  = alloc(196608);
    float* HP1  = alloc(196608);
    float* chFr = alloc(65536); float* chFi = alloc(65536);
    float* QpFr = alloc(65536); float* QpFi = alloc(65536);
    float* chW  = alloc(65536); float* QpW  = alloc(65536);
    float* chC  = alloc(65536); float* QpC  = alloc(65536);
    float* OFr  = alloc(65536); float* OFi  = alloc(65536);
    float* Ow   = alloc(65536); float* Oc   = alloc(65536);
    float* Pt   = alloc(156672);
    float* Mten = alloc(41616);
    float* ybv  = alloc(1024);
    if (ws_size < off * sizeof(float)) return;

    float* Uf = Ucat, *Uw = Ucat + 196608, *Uc = Ucat + 2 * 196608;
    const long SE48 = 2048 * 48, SE16 = 2048 * 16;

    // ---- prep / folds ----
    softmax_C3<<<dim3(4, 3), dim3(256), 0, stream>>>(Fp[0], Fp[1], Fp[2], fw);
    build_w2<<<dim3(576), dim3(256), 0, stream>>>(Wc[0], Wc[1], Wc[2], W2cat);
    build_G<<<dim3(3), dim3(256), 0, stream>>>(fw, Gm);
    build_ub<<<dim3(1), dim3(256), 0, stream>>>(bp[0], bp[1], bp[2], W2cat, ubv);
    init_bufs<<<dim3((147456 + 589824 + 720896 + 255) / 256), dim3(256), 0, stream>>>(W3cat, ubv);
    gen_dft<<<dim3(16384), dim3(256), 0, stream>>>(MAT0, MAT1);
    gen_dct<<<dim3(16384), dim3(256), 0, stream>>>(DCTD, DCTI);

    // W3_d = Wp_d^T @ W2_d   (M=1024, N=48, K=1024, split-K=4, atomic)
    for (int d = 0; d < 3; ++d)
        skinny<48, true, false, true><<<dim3(16, 1, 4), dim3(256), 0, stream>>>(
            Wp[d], W2cat + d * 49152, W3cat + d * 49152, 1024, 1024, 48, 48, 0, 0, 0, 1.f, 4);

    // U_d = query @ W3_d (+ub preloaded)  (M=4096, N=48, K=1024, KS=2, atomic, z=3)
    skinny<48, false, false, true><<<dim3(64, 1, 6), dim3(256), 0, stream>>>(
        query, W3cat, Ucat, 1024, 1024, 48, 48, 0, 49152, 196608, 1.f, 2);

    // Fourier forward: Tfr = MAT0 @ Uf, Tfi = MAT1 @ Uf  (per batch)
    skinny<48, false, false, true><<<dim3(32, 1, 8), dim3(256), 0, stream>>>(
        MAT0, Uf, Tfr, 2048, 2048, 48, 48, 0, SE48, SE48, 1.f, 4);
    skinny<48, false, false, true><<<dim3(32, 1, 8), dim3(256), 0, stream>>>(
        MAT1, Uf, Tfi, 2048, 2048, 48, 48, 0, SE48, SE48, 1.f, 4);
    // DCT forward: Tc = DCTD @ Uc
    skinny<48, false, false, true><<<dim3(32, 1, 8), dim3(256), 0, stream>>>(
        DCTD, Uc, Tc, 2048, 2048, 48, 48, 0, SE48, SE48, 1.f, 4);
    // Haar on Uw -> Tw
    for (int l = 0; l <= 10; ++l) {
        int h = 1024 >> l;
        const float* cur = (l == 0) ? Uw : ((l & 1) ? HP0 : HP1);
        float* nxt = (l & 1) ? HP1 : HP0;
        int tot = BB * h * 48;
        haar48<<<dim3((tot + 255) / 256), dim3(256), 0, stream>>>(cur, nxt, Tw, h);
    }
    // final approx row 0: after l=10, nxt=(10&1?HP1:HP0)=HP0 wait l=10 even -> HP0 holds 1-row approx
    // copy row0 of approx chain into Tw row 0 per batch: handled by haar48's nxt? No - do tiny fix:
    // (haar48 wrote approx into HP buffers; last level h=1 detail went to Tw[1], approx to HP0[0])
    // Fix: write Tw row 0 = HP0 row 0 (per batch)
    {
        // tiny copy kernel via haar48 trick is overkill; use hipMemcpyAsync D2D per batch
        for (int b = 0; b < BB; ++b)
            hipMemcpyAsync(Tw + (size_t)b * SE48, HP0 + (size_t)b * SE48,
                           48 * sizeof(float), hipMemcpyDeviceToDevice, stream);
    }

    // conv collapse + G fold
    conv_mix<true><<<dim3(8, 2), dim3(256), 0, stream>>>(Tfr, Tfi, Gm, bc[0], chFr, chFi, QpFr, QpFi);
    conv_mix<false><<<dim3(8, 2), dim3(256), 0, stream>>>(Tw, nullptr, Gm + 256, bc[1], chW, nullptr, QpW, nullptr);
    conv_mix<false><<<dim3(8, 2), dim3(256), 0, stream>>>(Tc, nullptr, Gm + 512, bc[2], chC, nullptr, QpC, nullptr);

    // flash attentions
    flash_c<<<dim3(128, 2), dim3(256), 0, stream>>>(QpFr, QpFi, chFr, chFi, OFr, OFi);
    flash_r<<<dim3(128, 2), dim3(256), 0, stream>>>(QpW, chW, Ow);
    flash_r<<<dim3(128, 2), dim3(256), 0, stream>>>(QpC, chC, Oc);

    // inverse transforms: Rf = (1/S)(MAT0@OFr + MAT1@OFi); Rc = DCTI@Oc
    skinny<16, false, false, true><<<dim3(32, 1, 8), dim3(256), 0, stream>>>(
        MAT0, OFr, Rf, 2048, 2048, 16, 16, 0, SE16, SE16, 1.f / 2048.f, 4);
    skinny<16, false, false, true><<<dim3(32, 1, 8), dim3(256), 0, stream>>>(
        MAT1, OFi, Rf, 2048, 2048, 16, 16, 0, SE16, SE16, 1.f / 2048.f, 4);
    skinny<16, false, false, true><<<dim3(32, 1, 8), dim3(256), 0, stream>>>(
        DCTI, Oc, Rc, 2048, 2048, 16, 16, 0, SE16, SE16, 1.f, 4);

    // MHA folds: Pt_l = iw @ fw_l^T (3072x16, pitch 17), col16 = ib
    skinny<16, false, true, false><<<dim3(48, 1, 3), dim3(256), 0, stream>>>(
        mha_iw, fw, Pt, 1024, 1024, 1024, 17, 0, 16384, 52224, 1.f, 1);
    ib_append<<<dim3(36), dim3(256), 0, stream>>>(mha_ib, Pt);
    build_M<<<dim3(144), dim3(256), 0, stream>>>(Pt, Mten);

    // MHA core -> MO (4096, 3072)
    mha_o<<<dim3(16, 16), dim3(256), 0, stream>>>(Rf, Ow, Rc, Pt, Mten, MO);

    // FT_l = (fusW_l @ ow), stored transposed into FTb (1024 x 3072)
    transpose_k<<<dim3(32, 32), dim3(256), 0, stream>>>(mha_ow, OWT, 1024, 1024);
    gemm(stream, fus_W, OWT, FTb, nullptr, 1024, 1024, 1024, 3072, 1024, 3072,
         1024, 0, 1024, 1.f, 0.f, 3);
    build_yb<<<dim3(4), dim3(256), 0, stream>>>(mha_ob, fus_W, fus_b, ybv);

    // out = MO @ FTb^T + yb   (M=4096, N=1024, K=3072)
    gemm(stream, MO, FTb, out, ybv, 4096, 1024, 3072, 3072, 3072, 1024,
         0, 0, 0, 1.f, 0.f, 1);
}

// Round 4
// 871.033 us; speedup vs baseline: 7.4595x; 1.2841x over previous
//
#include <hip/hip_runtime.h>
#include <cmath>

#define BB 2
#define SS_ 2048
#define EE 1024
#define CC 16

typedef __attribute__((ext_vector_type(8))) short short8v;
typedef __attribute__((ext_vector_type(4))) float floatx4;

// ---------------------------------------------------------------------------
// Split-bf16 (bf16x3) MFMA GEMM: C = alpha * A @ B^T [+ beta*C] [+ bias[n]]
// ---------------------------------------------------------------------------
#define BM 128
#define BN 128
#define BK 32
#define LDP 40

__device__ __forceinline__ void split4(const float4 v, short4& h, short4& l)
{
    unsigned ux = __float_as_uint(v.x), uy = __float_as_uint(v.y);
    unsigned uz = __float_as_uint(v.z), uw = __float_as_uint(v.w);
    h.x = (short)(ux >> 16); h.y = (short)(uy >> 16);
    h.z = (short)(uz >> 16); h.w = (short)(uw >> 16);
    float lx = v.x - __uint_as_float(ux & 0xFFFF0000u);
    float ly = v.y - __uint_as_float(uy & 0xFFFF0000u);
    float lz = v.z - __uint_as_float(uz & 0xFFFF0000u);
    float lw = v.w - __uint_as_float(uw & 0xFFFF0000u);
    l.x = (short)(__float_as_uint(lx) >> 16);
    l.y = (short)(__float_as_uint(ly) >> 16);
    l.z = (short)(__float_as_uint(lz) >> 16);
    l.w = (short)(__float_as_uint(lw) >> 16);
}

template<bool BETA, bool BIAS>
__launch_bounds__(256, 2)
__global__ void gemm_bf16x3(const float* __restrict__ A, const float* __restrict__ Bsrc,
                            float* __restrict__ C, const float* __restrict__ bias,
                            int K, int lda, int ldb, int ldc,
                            long sA, long sB, long sC, float alpha, float beta)
{
    __shared__ short sAh[BM * LDP], sAl[BM * LDP], sBh[BN * LDP], sBl[BN * LDP];
    const int bz = blockIdx.z;
    A += (size_t)bz * sA; Bsrc += (size_t)bz * sB; C += (size_t)bz * sC;
    const int tid = threadIdx.x;
    const int m0 = blockIdx.y * BM, n0 = blockIdx.x * BN;

    const int lr0 = tid >> 3;
    const int kc0 = (tid & 7) * 4;
    const float* pa = A + (size_t)(m0 + lr0) * lda + kc0;
    const float* pb = Bsrc + (size_t)(n0 + lr0) * ldb + kc0;

    float4 ra[4], rb[4];
    #pragma unroll
    for (int c = 0; c < 4; ++c) {
        ra[c] = *(const float4*)(pa + (size_t)c * 32 * lda);
        rb[c] = *(const float4*)(pb + (size_t)c * 32 * ldb);
    }

    const int lane = tid & 63, wid = tid >> 6;
    const int wm = wid >> 1, wn = wid & 1;
    const int lr = lane & 15, qd = lane >> 4;
    const int arow = wm * 64 + lr;
    const int brow = wn * 64 + lr;
    const int koff = qd * 8;

    floatx4 acc[4][4];
    #pragma unroll
    for (int i = 0; i < 4; ++i)
        #pragma unroll
        for (int j = 0; j < 4; ++j)
            acc[i][j] = (floatx4){0.f, 0.f, 0.f, 0.f};

    for (int kt = 0; kt < K; kt += BK) {
        __syncthreads();
        #pragma unroll
        for (int c = 0; c < 4; ++c) {
            const int row = lr0 + c * 32;
            short4 h, l;
            split4(ra[c], h, l);
            *(short4*)&sAh[row * LDP + kc0] = h;
            *(short4*)&sAl[row * LDP + kc0] = l;
            split4(rb[c], h, l);
            *(short4*)&sBh[row * LDP + kc0] = h;
            *(short4*)&sBl[row * LDP + kc0] = l;
        }
        __syncthreads();
        if (kt + BK < K) {
            pa += BK; pb += BK;
            #pragma unroll
            for (int c = 0; c < 4; ++c) {
                ra[c] = *(const float4*)(pa + (size_t)c * 32 * lda);
                rb[c] = *(const float4*)(pb + (size_t)c * 32 * ldb);
            }
        }
        short8v ah[4], al[4], bh[4], bl[4];
        #pragma unroll
        for (int i = 0; i < 4; ++i) {
            ah[i] = *(const short8v*)&sAh[(arow + i * 16) * LDP + koff];
            al[i] = *(const short8v*)&sAl[(arow + i * 16) * LDP + koff];
            bh[i] = *(const short8v*)&sBh[(brow + i * 16) * LDP + koff];
            bl[i] = *(const short8v*)&sBl[(brow + i * 16) * LDP + koff];
        }
        #pragma unroll
        for (int i = 0; i < 4; ++i)
            #pragma unroll
            for (int j = 0; j < 4; ++j)
                acc[i][j] = __builtin_amdgcn_mfma_f32_16x16x32_bf16(ah[i], bh[j], acc[i][j], 0, 0, 0);
        #pragma unroll
        for (int i = 0; i < 4; ++i)
            #pragma unroll
            for (int j = 0; j < 4; ++j)
                acc[i][j] = __builtin_amdgcn_mfma_f32_16x16x32_bf16(ah[i], bl[j], acc[i][j], 0, 0, 0);
        #pragma unroll
        for (int i = 0; i < 4; ++i)
            #pragma unroll
            for (int j = 0; j < 4; ++j)
                acc[i][j] = __builtin_amdgcn_mfma_f32_16x16x32_bf16(al[i], bh[j], acc[i][j], 0, 0, 0);
    }

    #pragma unroll
    for (int i = 0; i < 4; ++i) {
        const int mbase = m0 + wm * 64 + i * 16 + qd * 4;
        #pragma unroll
        for (int j = 0; j < 4; ++j) {
            const int n = n0 + wn * 64 + j * 16 + lr;
            float bv = 0.f;
            if (BIAS) bv = bias[n];
            #pragma unroll
            for (int r = 0; r < 4; ++r) {
                size_t off = (size_t)(mbase + r) * ldc + n;
                float v = alpha * acc[i][j][r];
                if (BETA) v += beta * C[off];
                if (BIAS) v += bv;
                C[off] = v;
            }
        }
    }
}

// ---------------------------------------------------------------------------
// Skinny VALU fp32 GEMM (single-operand version, used for U and Pt)
// ---------------------------------------------------------------------------
template<int NT, bool TA, bool TB, bool ATOMIC>
__launch_bounds__(256)
__global__ void skinny(const float* __restrict__ A, const float* __restrict__ Bs,
                       float* __restrict__ C,
                       int K, int lda, int ldb, int ldc,
                       long sA, long sB, long sC, float alpha, int KS)
{
    const int zb = blockIdx.z / KS, ks = blockIdx.z - zb * KS;
    A += (size_t)zb * sA; Bs += (size_t)zb * sB; C += (size_t)zb * sC;
    const int klen = K / KS;
    const int k0 = ks * klen;
    const int m0 = blockIdx.x * 64;
    __shared__ float sa[32][68];
    __shared__ float sb[32][(NT == 48) ? 52 : 20];
    const int tid = threadIdx.x;
    const int tm = tid >> 4, tn = tid & 15;
    constexpr int CN = NT / 16;
    float acc[4][CN] = {};

    for (int kc = k0; kc < k0 + klen; kc += 32) {
        __syncthreads();
        if (!TA) {
            #pragma unroll
            for (int cx = 0; cx < 2; ++cx) {
                int lin = cx * 256 + tid;
                int r = lin >> 3, c4 = (lin & 7) * 4;
                float4 v = *(const float4*)(A + (size_t)(m0 + r) * lda + kc + c4);
                sa[c4 + 0][r] = v.x; sa[c4 + 1][r] = v.y; sa[c4 + 2][r] = v.z; sa[c4 + 3][r] = v.w;
            }
        } else {
            #pragma unroll
            for (int cx = 0; cx < 2; ++cx) {
                int lin = cx * 256 + tid;
                int kk = lin >> 4, c4 = (lin & 15) * 4;
                *(float4*)&sa[kk][c4] = *(const float4*)(A + (size_t)(kc + kk) * lda + m0 + c4);
            }
        }
        if (!TB) {
            constexpr int NF4 = NT / 4;
            for (int lin = tid; lin < 32 * NF4; lin += 256) {
                int kk = lin / NF4, c4 = (lin % NF4) * 4;
                *(float4*)&sb[kk][c4] = *(const float4*)(Bs + (size_t)(kc + kk) * ldb + c4);
            }
        } else {
            for (int lin = tid; lin < 128; lin += 256) {
                int n = lin >> 3, c4 = (lin & 7) * 4;
                float4 v = *(const float4*)(Bs + (size_t)n * ldb + kc + c4);
                sb[c4 + 0][n] = v.x; sb[c4 + 1][n] = v.y; sb[c4 + 2][n] = v.z; sb[c4 + 3][n] = v.w;
            }
        }
        __syncthreads();
        #pragma unroll
        for (int kk = 0; kk < 32; ++kk) {
            float4 av = *(const float4*)&sa[kk][tm * 4];
            #pragma unroll
            for (int c = 0; c < CN; ++c) {
                float bv = sb[kk][tn * CN + c];
                acc[0][c] = fmaf(av.x, bv, acc[0][c]);
                acc[1][c] = fmaf(av.y, bv, acc[1][c]);
                acc[2][c] = fmaf(av.z, bv, acc[2][c]);
                acc[3][c] = fmaf(av.w, bv, acc[3][c]);
            }
        }
    }
    #pragma unroll
    for (int r = 0; r < 4; ++r)
        #pragma unroll
        for (int c = 0; c < CN; ++c) {
            int m = m0 + tm * 4 + r, n = tn * CN + c;
            float v = alpha * acc[r][c];
            if (ATOMIC) atomicAdd(&C[(size_t)m * ldc + n], v);
            else C[(size_t)m * ldc + n] = v;
        }
}

// ---------------------------------------------------------------------------
// Multi-operand skinny: 3 independent products in one launch (atomic).
// z = sel*(nb*KS) + zb*KS + ks; A shared per sel (sel-batch-invariant).
// ---------------------------------------------------------------------------
template<int NT, bool TA>
__launch_bounds__(256)
__global__ void skinny_multi(const float* __restrict__ A0, const float* __restrict__ A1,
                             const float* __restrict__ A2,
                             const float* __restrict__ B0, const float* __restrict__ B1,
                             const float* __restrict__ B2,
                             float* __restrict__ C0, float* __restrict__ C1,
                             float* __restrict__ C2,
                             int K, int lda, int ldb, int ldc,
                             long sB, long sC, float al0, float al1, float al2,
                             int nb, int KS)
{
    const int z = blockIdx.z;
    const int sel = z / (nb * KS);
    const int rem = z - sel * (nb * KS);
    const int zb = rem / KS, ks = rem - zb * KS;
    const float* A = sel == 0 ? A0 : (sel == 1 ? A1 : A2);
    const float* Bs = (sel == 0 ? B0 : (sel == 1 ? B1 : B2)) + (size_t)zb * sB;
    float* C = (sel == 0 ? C0 : (sel == 1 ? C1 : C2)) + (size_t)zb * sC;
    const float alpha = sel == 0 ? al0 : (sel == 1 ? al1 : al2);
    const int klen = K / KS;
    const int k0 = ks * klen;
    const int m0 = blockIdx.x * 64;
    __shared__ float sa[32][68];
    __shared__ float sb[32][(NT == 48) ? 52 : 20];
    const int tid = threadIdx.x;
    const int tm = tid >> 4, tn = tid & 15;
    constexpr int CN = NT / 16;
    float acc[4][CN] = {};

    for (int kc = k0; kc < k0 + klen; kc += 32) {
        __syncthreads();
        if (!TA) {
            #pragma unroll
            for (int cx = 0; cx < 2; ++cx) {
                int lin = cx * 256 + tid;
                int r = lin >> 3, c4 = (lin & 7) * 4;
                float4 v = *(const float4*)(A + (size_t)(m0 + r) * lda + kc + c4);
                sa[c4 + 0][r] = v.x; sa[c4 + 1][r] = v.y; sa[c4 + 2][r] = v.z; sa[c4 + 3][r] = v.w;
            }
        } else {
            #pragma unroll
            for (int cx = 0; cx < 2; ++cx) {
                int lin = cx * 256 + tid;
                int kk = lin >> 4, c4 = (lin & 15) * 4;
                *(float4*)&sa[kk][c4] = *(const float4*)(A + (size_t)(kc + kk) * lda + m0 + c4);
            }
        }
        {
            constexpr int NF4 = NT / 4;
            for (int lin = tid; lin < 32 * NF4; lin += 256) {
                int kk = lin / NF4, c4 = (lin % NF4) * 4;
                *(float4*)&sb[kk][c4] = *(const float4*)(Bs + (size_t)(kc + kk) * ldb + c4);
            }
        }
        __syncthreads();
        #pragma unroll
        for (int kk = 0; kk < 32; ++kk) {
            float4 av = *(const float4*)&sa[kk][tm * 4];
            #pragma unroll
            for (int c = 0; c < CN; ++c) {
                float bv = sb[kk][tn * CN + c];
                acc[0][c] = fmaf(av.x, bv, acc[0][c]);
                acc[1][c] = fmaf(av.y, bv, acc[1][c]);
                acc[2][c] = fmaf(av.z, bv, acc[2][c]);
                acc[3][c] = fmaf(av.w, bv, acc[3][c]);
            }
        }
    }
    #pragma unroll
    for (int r = 0; r < 4; ++r)
        #pragma unroll
        for (int c = 0; c < CN; ++c) {
            int m = m0 + tm * 4 + r, n = tn * CN + c;
            atomicAdd(&C[(size_t)m * ldc + n], alpha * acc[r][c]);
        }
}

// ---------------------------------------------------------------------------
// Trig matrices (DFT + DCT in one launch)
// ---------------------------------------------------------------------------
__global__ void gen_trig(float* __restrict__ Cc, float* __restrict__ Sn,
                         float* __restrict__ D, float* __restrict__ I)
{
    size_t idx = (size_t)blockIdx.x * 256 + threadIdx.x;   // 2 * 4194304
    if (idx < 4194304) {
        int k = (int)(idx >> 11);
        int n = (int)(idx & 2047);
        int m = (k * n) & 2047;
        float ang = (float)(6.283185307179586 * (double)m / 2048.0);
        Cc[idx] = cosf(ang);
        Sn[idx] = -sinf(ang);
    } else {
        idx -= 4194304;
        int i = (int)(idx >> 11);
        int j = (int)(idx & 2047);
        const float r1 = 0.022097086912079608f;
        const float r2 = 0.03125f;
        const float pif = 3.14159265358979323846f;
        float a  = (pif * (float)i) * (float)(2 * j + 1) / 4096.0f;
        D[idx] = cosf(a) * (i == 0 ? r1 : r2);
        float ai = (pif * (float)j) * (float)(2 * i + 1) / 4096.0f;
        I[idx] = cosf(ai) * (j == 0 ? r1 : r2);
    }
}

// ---------------------------------------------------------------------------
// fw softmax + G = (1/32) fw@fw^T, fused. grid 3 (one block per domain).
// ---------------------------------------------------------------------------
__launch_bounds__(256)
__global__ void prep_fw_G(const float* __restrict__ F0, const float* __restrict__ F1,
                          const float* __restrict__ F2, float* __restrict__ fw,
                          float* __restrict__ G)
{
    const int d = blockIdx.x, tid = threadIdx.x;
    const float* Fp = d == 0 ? F0 : (d == 1 ? F1 : F2);
    __shared__ float sf[CC * 1028];        // pitch 1028 -> 2-way-only conflicts
    #pragma unroll
    for (int k = 0; k < 4; ++k) {
        int e = tid + k * 256;
        float v[CC]; float m = -3.4e38f;
        #pragma unroll
        for (int c = 0; c < CC; ++c) { v[c] = Fp[c * EE + e]; m = fmaxf(m, v[c]); }
        float s = 0.f;
        #pragma unroll
        for (int c = 0; c < CC; ++c) { v[c] = expf(v[c] - m); s += v[c]; }
        float inv = 1.f / s;
        #pragma unroll
        for (int c = 0; c < CC; ++c) {
            float o = v[c] * inv;
            fw[d * CC * EE + c * EE + e] = o;
            sf[c * 1028 + e] = o;
        }
    }
    __syncthreads();
    const int a = tid >> 4, b = tid & 15;
    const float4* pa = (const float4*)&sf[a * 1028];
    const float4* pb = (const float4*)&sf[b * 1028];
    float s = 0.f;
    for (int i = 0; i < 256; ++i) {
        float4 x = pa[i], y = pb[i];
        s += x.x * y.x + x.y * y.y + x.z * y.z + x.w * y.w;
    }
    G[d * 256 + a * 16 + b] = s * 0.03125f;
}

__global__ void build_w2(const float* __restrict__ W0, const float* __restrict__ W1,
                         const float* __restrict__ W2_, float* __restrict__ W2cat)
{
    int idx = blockIdx.x * 256 + threadIdx.x;
    if (idx >= 3 * CC * EE * 3) return;
    int d = idx / 49152, r = idx % 49152;
    const float* Wc = d == 0 ? W0 : (d == 1 ? W1 : W2_);
    int c = r / 3072, e = (r % 3072) / 3, k = r % 3;
    W2cat[d * 49152 + e * 48 + c * 3 + k] = Wc[r];
}

// ub[d*48+c] = sum_e bp_d[e] * W2cat[d][e][c]; grid 3, block 256
__global__ void build_ub2(const float* __restrict__ b0, const float* __restrict__ b1,
                          const float* __restrict__ b2, const float* __restrict__ W2cat,
                          float* __restrict__ ub)
{
    const int d = blockIdx.x, tid = threadIdx.x;
    const float* bp = d == 0 ? b0 : (d == 1 ? b1 : b2);
    __shared__ float red[4][48];
    const int c = tid & 63, sl = tid >> 6;
    float s = 0.f;
    if (c < 48)
        for (int e = sl; e < EE; e += 4)
            s += bp[e] * W2cat[d * 49152 + e * 48 + c];
    if (c < 48) red[sl][c] = s;
    __syncthreads();
    if (tid < 48) ub[d * 48 + tid] = red[0][tid] + red[1][tid] + red[2][tid] + red[3][tid];
}

// init: [W3cat zeros | Ucat = ub broadcast | Tfr,Tfi,Tc,Rf,Rc zeros]
__global__ void init_bufs(float* __restrict__ base, const float* __restrict__ ub)
{
    size_t idx = (size_t)blockIdx.x * 256 + threadIdx.x;
    const size_t W3N = 147456, UN = 589824, ZN = 720896;
    if (idx >= W3N + UN + ZN) return;
    float v = 0.f;
    if (idx >= W3N && idx < W3N + UN) {
        size_t r = idx - W3N;
        int d = (int)(r / 196608), c = (int)(r % 48);
        v = ub[d * 48 + c];
    }
    base[idx] = v;
}

__global__ void ib_append(const float* __restrict__ ib, float* __restrict__ Pt)
{
    int idx = blockIdx.x * 256 + threadIdx.x;
    if (idx >= 9216) return;
    int d = idx / 3072, j = idx % 3072;
    Pt[d * 52224 + j * 17 + 16] = ib[j];
}

__launch_bounds__(256)
__global__ void build_M(const float* __restrict__ Pt, float* __restrict__ Mten)
{
    int blk = blockIdx.x;             // h*9 + l*3 + m
    int h = blk / 9, lm = blk % 9;
    int l = lm / 3, m = lm % 3;
    __shared__ float sQ[64][17], sK[64][17];
    for (int lin = threadIdx.x; lin < 1088; lin += 256) {
        int d = lin / 17, a = lin % 17;
        sQ[d][a] = Pt[l * 52224 + (size_t)(h * 64 + d) * 17 + a];
        sK[d][a] = Pt[m * 52224 + (size_t)(1024 + h * 64 + d) * 17 + a];
    }
    __syncthreads();
    for (int o = threadIdx.x; o < 289; o += 256) {
        int a = o / 17, b = o % 17;
        float s = 0.f;
        for (int d = 0; d < 64; ++d) s += sQ[d][a] * sK[d][b];
        Mten[(size_t)blk * 289 + o] = 0.125f * s;
    }
}

// yb[n] = fus_b[n] + sum_j ob[j%1024]*fus_W[n][j]; block = 4 rows x 64 lanes
__launch_bounds__(256)
__global__ void build_yb2(const float* __restrict__ ob, const float* __restrict__ fus_W,
                          const float* __restrict__ fus_b, float* __restrict__ yb)
{
    const int n = blockIdx.x * 4 + (threadIdx.x >> 6);
    const int lane = threadIdx.x & 63;
    float s = 0.f;
    for (int j = lane; j < 3072; j += 64)
        s += ob[j & 1023] * fus_W[(size_t)n * 3072 + j];
    #pragma unroll
    for (int off = 32; off > 0; off >>= 1) s += __shfl_xor(s, off, 64);
    if (lane == 0) yb[n] = s + fus_b[n];
}

__global__ void transpose_k(const float* __restrict__ X, float* __restrict__ XT,
                            int rows, int cols)
{
    __shared__ float tile[32][33];
    const int lx = threadIdx.x & 31, ly = threadIdx.x >> 5;
    const int r0 = blockIdx.y * 32, c0 = blockIdx.x * 32;
    #pragma unroll
    for (int p = 0; p < 4; ++p)
        tile[ly + p * 8][lx] = X[(size_t)(r0 + ly + p * 8) * cols + c0 + lx];
    __syncthreads();
    #pragma unroll
    for (int p = 0; p < 4; ++p)
        XT[(size_t)(c0 + ly + p * 8) * rows + r0 + lx] = tile[lx][ly + p * 8];
}

// ---------------------------------------------------------------------------
// Full Haar pyramid in one kernel. grid (48/8, B); cols independent.
// ---------------------------------------------------------------------------
#define HCG 8
__launch_bounds__(256)
__global__ void haar_all(const float* __restrict__ U, float* __restrict__ T)
{
    __shared__ float A[2048 * HCG];     // 64 KB
    __shared__ float Pp[1024 * HCG];    // 32 KB
    const int g = blockIdx.x, b = blockIdx.y, tid = threadIdx.x;
    const float isq = 0.70710678118654752440f;
    for (int lin = tid; lin < 2048 * 2; lin += 256) {
        int r = lin >> 1, c4 = (lin & 1) * 4;
        *(float4*)&A[r * HCG + c4] =
            *(const float4*)(U + ((size_t)(b * 2048 + r)) * 48 + g * HCG + c4);
    }
    __syncthreads();
    float* cur = A; float* nxt = Pp;
    for (int h = 1024; h >= 1; h >>= 1) {
        for (int lin = tid; lin < h * HCG; lin += 256) {
            int i = lin >> 3, c = lin & 7;
            float e = cur[(2 * i) * HCG + c], o = cur[(2 * i + 1) * HCG + c];
            T[((size_t)(b * 2048 + h + i)) * 48 + g * HCG + c] = (e - o) * isq;
            nxt[i * HCG + c] = (e + o) * isq;
        }
        __syncthreads();
        float* t = cur; cur = nxt; nxt = t;
    }
    if (tid < HCG) T[((size_t)(b * 2048)) * 48 + g * HCG + tid] = cur[tid];
}

// ---------------------------------------------------------------------------
// conv collapse + G fold. grid (2048/64, B); block 256 = 64 rows x 4 lanes.
// ---------------------------------------------------------------------------
template<bool CPLX>
__launch_bounds__(256)
__global__ void conv_mix2(const float* __restrict__ Tre, const float* __restrict__ Tim,
                          const float* __restrict__ G, const float* __restrict__ bc,
                          float* __restrict__ chR, float* __restrict__ chI,
                          float* __restrict__ QR, float* __restrict__ QI)
{
    const int s0 = blockIdx.x * 64, b = blockIdx.y;
    const int tid = threadIdx.x;
    __shared__ float sR[66 * 49];
    __shared__ float sI[CPLX ? 66 * 49 : 1];
    __shared__ float scr[64 * 17];
    __shared__ float sci[CPLX ? 64 * 17 : 1];
    __shared__ float sG[256];
    if (tid < 256) sG[tid] = G[tid];
    for (int lin = tid; lin < 66 * 12; lin += 256) {
        int r = lin / 12, c4 = (lin % 12) * 4;
        int srow = s0 - 1 + r;
        float4 v = {0.f, 0.f, 0.f, 0.f}, w = {0.f, 0.f, 0.f, 0.f};
        if (srow >= 0 && srow < 2048) {
            v = *(const float4*)(Tre + ((size_t)(b * 2048 + srow)) * 48 + c4);
            if (CPLX) w = *(const float4*)(Tim + ((size_t)(b * 2048 + srow)) * 48 + c4);
        }
        sR[r * 49 + c4] = v.x; sR[r * 49 + c4 + 1] = v.y;
        sR[r * 49 + c4 + 2] = v.z; sR[r * 49 + c4 + 3] = v.w;
        if (CPLX) {
            sI[r * 49 + c4] = w.x; sI[r * 49 + c4 + 1] = w.y;
            sI[r * 49 + c4 + 2] = w.z; sI[r * 49 + c4 + 3] = w.w;
        }
    }
    __syncthreads();
    const int row = tid >> 2, ln = tid & 3;
    float ch[4], chi[4];
    #pragma unroll
    for (int j = 0; j < 4; ++j) {
        int c = ln * 4 + j;
        float bcv = bc[c];
        ch[j] = sR[row * 49 + 3 * c] + sR[(row + 1) * 49 + 3 * c + 1]
              + sR[(row + 2) * 49 + 3 * c + 2] + bcv;
        scr[row * 17 + c] = ch[j];
        if (CPLX) {
            chi[j] = sI[row * 49 + 3 * c] + sI[(row + 1) * 49 + 3 * c + 1]
                   + sI[(row + 2) * 49 + 3 * c + 2] + bcv;
            sci[row * 17 + c] = chi[j];
        }
    }
    size_t ro = ((size_t)(b * 2048 + s0 + row)) * 16 + ln * 4;
    *(float4*)(chR + ro) = *(float4*)&ch[0];
    if (CPLX) *(float4*)(chI + ro) = *(float4*)&chi[0];
    __syncthreads();
    float qp[4], qpi[4];
    #pragma unroll
    for (int j = 0; j < 4; ++j) { qp[j] = 0.f; qpi[j] = 0.f; }
    #pragma unroll
    for (int c = 0; c < 16; ++c) {
        float cv = scr[row * 17 + c];
        float cvi = CPLX ? sci[row * 17 + c] : 0.f;
        #pragma unroll
        for (int j = 0; j < 4; ++j) {
            float g = sG[c * 16 + ln * 4 + j];
            qp[j] = fmaf(cv, g, qp[j]);
            if (CPLX) qpi[j] = fmaf(cvi, g, qpi[j]);
        }
    }
    *(float4*)(QR + ro) = *(float4*)&qp[0];
    if (CPLX) *(float4*)(QI + ro) = *(float4*)&qpi[0];
}

// ---------------------------------------------------------------------------
// Flash attention rank-16, real. One wave per Q-row; keys from L2.
// grid (S/4, B), block 256 (4 waves).
// ---------------------------------------------------------------------------
__launch_bounds__(256)
__global__ void flash_r2(const float* __restrict__ Qp, const float* __restrict__ ch,
                         float* __restrict__ O)
{
    const int b = blockIdx.y;
    const int w = threadIdx.x >> 6, lane = threadIdx.x & 63;
    const int s = blockIdx.x * 4 + w;
    const float* qrow = Qp + ((size_t)(b * 2048 + s)) * 16;
    float q[16];
    #pragma unroll
    for (int j = 0; j < 4; ++j) *(float4*)&q[j * 4] = *(const float4*)(qrow + j * 4);
    const float* chb = ch + (size_t)b * 2048 * 16;
    float m = -3.4e38f, l = 0.f;
    float acc[16] = {};
    for (int t = lane; t < 2048; t += 64) {
        const float* kp = chb + (size_t)t * 16;
        float kv[16];
        #pragma unroll
        for (int j = 0; j < 4; ++j) *(float4*)&kv[j * 4] = *(const float4*)(kp + j * 4);
        float sc = 0.f;
        #pragma unroll
        for (int e = 0; e < 16; ++e) sc = fmaf(q[e], kv[e], sc);
        float mn = fmaxf(m, sc);
        float al = __expf(m - mn), p = __expf(sc - mn);
        l = l * al + p;
        #pragma unroll
        for (int e = 0; e < 16; ++e) acc[e] = fmaf(acc[e], al, p * kv[e]);
        m = mn;
    }
    #pragma unroll
    for (int off = 1; off < 64; off <<= 1) {
        float m2 = __shfl_xor(m, off, 64);
        float l2 = __shfl_xor(l, off, 64);
        float mn = fmaxf(m, m2);
        float ra = __expf(m - mn), rb = __expf(m2 - mn);
        l = l * ra + l2 * rb;
        #pragma unroll
        for (int e = 0; e < 16; ++e) {
            float a2 = __shfl_xor(acc[e], off, 64);
            acc[e] = acc[e] * ra + a2 * rb;
        }
        m = mn;
    }
    if (lane < 4) {
        float inv = 1.f / l;
        float4 o4 = {acc[lane * 4] * inv, acc[lane * 4 + 1] * inv,
                     acc[lane * 4 + 2] * inv, acc[lane * 4 + 3] * inv};
        *(float4*)(O + ((size_t)(b * 2048 + s)) * 16 + lane * 4) = o4;
    }
}

// Complex flash: w = softmax(Re s); cw = w * s/|s|; O = cw @ (chR + i chI)
__launch_bounds__(256)
__global__ void flash_c2(const float* __restrict__ QpR, const float* __restrict__ QpI,
                         const float* __restrict__ chR, const float* __restrict__ chI,
                         float* __restrict__ OR_, float* __restrict__ OI_)
{
    const int b = blockIdx.y;
    const int w = threadIdx.x >> 6, lane = threadIdx.x & 63;
    const int s = blockIdx.x * 4 + w;
    float qr[16], qi[16];
    {
        const float* qrow = QpR + ((size_t)(b * 2048 + s)) * 16;
        const float* qrowI = QpI + ((size_t)(b * 2048 + s)) * 16;
        #pragma unroll
        for (int j = 0; j < 4; ++j) {
            *(float4*)&qr[j * 4] = *(const float4*)(qrow + j * 4);
            *(float4*)&qi[j * 4] = *(const float4*)(qrowI + j * 4);
        }
    }
    const float* cbR = chR + (size_t)b * 2048 * 16;
    const float* cbI = chI + (size_t)b * 2048 * 16;
    float m = -3.4e38f, l = 0.f;
    float aR[16] = {}, aI[16] = {};
    for (int t = lane; t < 2048; t += 64) {
        float kr[16], ki[16];
        #pragma unroll
        for (int j = 0; j < 4; ++j) {
            *(float4*)&kr[j * 4] = *(const float4*)(cbR + (size_t)t * 16 + j * 4);
            *(float4*)&ki[j * 4] = *(const float4*)(cbI + (size_t)t * 16 + j * 4);
        }
        float sre = 0.f, sim = 0.f;
        #pragma unroll
        for (int e = 0; e < 16; ++e) {
            sre = fmaf(qr[e], kr[e], sre); sre = fmaf(-qi[e], ki[e], sre);
            sim = fmaf(qr[e], ki[e], sim); sim = fmaf(qi[e], kr[e], sim);
        }
        float mn = fmaxf(m, sre);
        float al = __expf(m - mn), p = __expf(sre - mn);
        l = l * al + p;
        float rr = sqrtf(sre * sre + sim * sim);
        float iv = (rr > 0.f) ? (p / rr) : 0.f;
        float wr = (rr > 0.f) ? iv * sre : p;
        float wi = (rr > 0.f) ? iv * sim : 0.f;
        #pragma unroll
        for (int e = 0; e < 16; ++e) {
            aR[e] = fmaf(aR[e], al, wr * kr[e] - wi * ki[e]);
            aI[e] = fmaf(aI[e], al, wr * ki[e] + wi * kr[e]);
        }
        m = mn;
    }
    #pragma unroll
    for (int off = 1; off < 64; off <<= 1) {
        float m2 = __shfl_xor(m, off, 64);
        float l2 = __shfl_xor(l, off, 64);
        float mn = fmaxf(m, m2);
        float ra = __expf(m - mn), rb = __expf(m2 - mn);
        l = l * ra + l2 * rb;
        #pragma unroll
        for (int e = 0; e < 16; ++e) {
            float a2 = __shfl_xor(aR[e], off, 64);
            aR[e] = aR[e] * ra + a2 * rb;
            float b2 = __shfl_xor(aI[e], off, 64);
            aI[e] = aI[e] * ra + b2 * rb;
        }
        m = mn;
    }
    float inv = 1.f / l;
    size_t ro = ((size_t)(b * 2048 + s)) * 16;
    if (lane < 4) {
        float4 o4 = {aR[lane * 4] * inv, aR[lane * 4 + 1] * inv,
                     aR[lane * 4 + 2] * inv, aR[lane * 4 + 3] * inv};
        *(float4*)(OR_ + ro + lane * 4) = o4;
    } else if (lane < 8) {
        int j = lane - 4;
        float4 o4 = {aI[j * 4] * inv, aI[j * 4 + 1] * inv,
                     aI[j * 4 + 2] * inv, aI[j * 4 + 3] * inv};
        *(float4*)(OI_ + ro + j * 4) = o4;
    }
}

// ---------------------------------------------------------------------------
// MHA over L=3 via rank-17 bilinear forms -> MO (4096, 3072). grid (16,16).
// ---------------------------------------------------------------------------
__launch_bounds__(256)
__global__ void mha_o(const float* __restrict__ R0, const float* __restrict__ R1,
                      const float* __restrict__ R2, const float* __restrict__ Pt,
                      const float* __restrict__ Mten, float* __restrict__ MO)
{
    const int tid = threadIdx.x;
    const int p = blockIdx.x * 256 + tid;
    const int h = blockIdx.y;
    __shared__ float sPv[3 * 64 * 20];
    __shared__ float sM[9 * 17 * 20];
    for (int lin = tid; lin < 3264; lin += 256) {
        int mm = lin / 1088, rem = lin % 1088;
        int rr = rem / 17, a = rem % 17;
        sPv[(mm * 64 + rr) * 20 + a] = Pt[mm * 52224 + (size_t)(2048 + h * 64 + rr) * 17 + a];
    }
    for (int lin = tid; lin < 2601; lin += 256) {
        int lm = lin / 289, rem = lin % 289;
        int a = rem / 17, bq = rem % 17;
        sM[lm * 340 + a * 20 + bq] = Mten[(size_t)h * 2601 + lin];
    }
    __syncthreads();
    float R[3][16];
    float4 R4[3][4];
    #pragma unroll
    for (int j = 0; j < 4; ++j) {
        R4[0][j] = *(const float4*)(R0 + (size_t)p * 16 + j * 4);
        R4[1][j] = *(const float4*)(R1 + (size_t)p * 16 + j * 4);
        R4[2][j] = *(const float4*)(R2 + (size_t)p * 16 + j * 4);
        *(float4*)&R[0][j * 4] = R4[0][j];
        *(float4*)&R[1][j * 4] = R4[1][j];
        *(float4*)&R[2][j * 4] = R4[2][j];
    }
    float w[3][3];
    #pragma unroll
    for (int l = 0; l < 3; ++l) {
        float sc[3];
        #pragma unroll
        for (int mm = 0; mm < 3; ++mm) {
            const float* Mp = &sM[(l * 3 + mm) * 340];
            float s = 0.f;
            #pragma unroll
            for (int a = 0; a < 17; ++a) {
                const float* mr = Mp + a * 20;
                float4 m0 = *(const float4*)(mr), m1 = *(const float4*)(mr + 4);
                float4 m2 = *(const float4*)(mr + 8), m3 = *(const float4*)(mr + 12);
                float t = mr[16];
                t = fmaf(m0.x, R4[mm][0].x, t); t = fmaf(m0.y, R4[mm][0].y, t);
                t = fmaf(m0.z, R4[mm][0].z, t); t = fmaf(m0.w, R4[mm][0].w, t);
                t = fmaf(m1.x, R4[mm][1].x, t); t = fmaf(m1.y, R4[mm][1].y, t);
                t = fmaf(m1.z, R4[mm][1].z, t); t = fmaf(m1.w, R4[mm][1].w, t);
                t = fmaf(m2.x, R4[mm][2].x, t); t = fmaf(m2.y, R4[mm][2].y, t);
                t = fmaf(m2.z, R4[mm][2].z, t); t = fmaf(m2.w, R4[mm][2].w, t);
                t = fmaf(m3.x, R4[mm][3].x, t); t = fmaf(m3.y, R4[mm][3].y, t);
                t = fmaf(m3.z, R4[mm][3].z, t); t = fmaf(m3.w, R4[mm][3].w, t);
                float ra = (a < 16) ? R[l][a] : 1.f;
                s = fmaf(ra, t, s);
            }
            sc[mm] = s;
        }
        float mx = fmaxf(sc[0], fmaxf(sc[1], sc[2]));
        float e0 = expf(sc[0] - mx), e1 = expf(sc[1] - mx), e2 = expf(sc[2] - mx);
        float inv = 1.f / (e0 + e1 + e2);
        w[l][0] = e0 * inv; w[l][1] = e1 * inv; w[l][2] = e2 * inv;
    }
    #pragma unroll
    for (int d4 = 0; d4 < 16; ++d4) {
        float4 vm[3];
        #pragma unroll
        for (int mm = 0; mm < 3; ++mm) {
            float vx[4];
            #pragma unroll
            for (int r = 0; r < 4; ++r) {
                const float* pv = &sPv[(mm * 64 + d4 * 4 + r) * 20];
                float4 p0 = *(const float4*)(pv), p1 = *(const float4*)(pv + 4);
                float4 p2 = *(const float4*)(pv + 8), p3 = *(const float4*)(pv + 12);
                float t = pv[16];
                t = fmaf(R4[mm][0].x, p0.x, t); t = fmaf(R4[mm][0].y, p0.y, t);
                t = fmaf(R4[mm][0].z, p0.z, t); t = fmaf(R4[mm][0].w, p0.w, t);
                t = fmaf(R4[mm][1].x, p1.x, t); t = fmaf(R4[mm][1].y, p1.y, t);
                t = fmaf(R4[mm][1].z, p1.z, t); t = fmaf(R4[mm][1].w, p1.w, t);
                t = fmaf(R4[mm][2].x, p2.x, t); t = fmaf(R4[mm][2].y, p2.y, t);
                t = fmaf(R4[mm][2].z, p2.z, t); t = fmaf(R4[mm][2].w, p2.w, t);
                t = fmaf(R4[mm][3].x, p3.x, t); t = fmaf(R4[mm][3].y, p3.y, t);
                t = fmaf(R4[mm][3].z, p3.z, t); t = fmaf(R4[mm][3].w, p3.w, t);
                vx[r] = t;
            }
            vm[mm] = (float4){vx[0], vx[1], vx[2], vx[3]};
        }
        #pragma unroll
        for (int l = 0; l < 3; ++l) {
            float4 o4;
            o4.x = w[l][0] * vm[0].x + w[l][1] * vm[1].x + w[l][2] * vm[2].x;
            o4.y = w[l][0] * vm[0].y + w[l][1] * vm[1].y + w[l][2] * vm[2].y;
            o4.z = w[l][0] * vm[0].z + w[l][1] * vm[1].z + w[l][2] * vm[2].z;
            o4.w = w[l][0] * vm[0].w + w[l][1] * vm[1].w + w[l][2] * vm[2].w;
            *(float4*)(MO + (size_t)p * 3072 + l * 1024 + h * 64 + d4 * 4) = o4;
        }
    }
}

// ---------------------------------------------------------------------------
// Host
// ---------------------------------------------------------------------------
static void gemm(hipStream_t st, const float* A, const float* Bsrc, float* C,
                 const float* bias, int M, int N, int K, int lda, int ldb, int ldc,
                 long sA, long sB, long sC, float alpha, float beta, int batch)
{
    dim3 g(N / BN, M / BM, batch), blk(256);
    bool ub = (beta != 0.0f), ubi = (bias != nullptr);
#define GCASE(BE, BI) gemm_bf16x3<BE, BI><<<g, blk, 0, st>>>(A, Bsrc, C, bias, K, lda, ldb, ldc, sA, sB, sC, alpha, beta)
    if (ub)  { if (ubi) GCASE(true, true);  else GCASE(true, false); }
    else     { if (ubi) GCASE(false, true); else GCASE(false, false); }
#undef GCASE
}

extern "C" void kernel_launch(void* const* d_in, const int* in_sizes, int n_in,
                              void* d_out, int out_size, void* d_ws, size_t ws_size,
                              hipStream_t stream)
{
    const float* query = (const float*)d_in[0];
    const float* Wp[3] = {(const float*)d_in[1], (const float*)d_in[6],  (const float*)d_in[11]};
    const float* bp[3] = {(const float*)d_in[2], (const float*)d_in[7],  (const float*)d_in[12]};
    const float* Wc[3] = {(const float*)d_in[3], (const float*)d_in[8],  (const float*)d_in[13]};
    const float* bc[3] = {(const float*)d_in[4], (const float*)d_in[9],  (const float*)d_in[14]};
    const float* Fp[3] = {(const float*)d_in[5], (const float*)d_in[10], (const float*)d_in[15]};
    const float* mha_iw = (const float*)d_in[16];
    const float* mha_ib = (const float*)d_in[17];
    const float* mha_ow = (const float*)d_in[18];
    const float* mha_ob = (const float*)d_in[19];
    const float* fus_W  = (const float*)d_in[20];
    const float* fus_b  = (const float*)d_in[21];
    float* out = (float*)d_out;
    float* ws = (float*)d_ws;

    size_t off = 0;
    auto alloc = [&](size_t n) { float* p = ws + off; off += n; return p; };
    float* MAT0 = alloc(4194304);
    float* MAT1 = alloc(4194304);
    float* DCTD = alloc(4194304);
    float* DCTI = alloc(4194304);
    float* MO   = alloc((size_t)4096 * 3072);
    float* FTb  = alloc((size_t)1024 * 3072);
    float* OWT  = alloc((size_t)1024 * 1024);
    float* fw   = alloc(3 * 16 * 1024);
    float* W2cat = alloc(147456);
    float* ubv  = alloc(256);
    float* Gm   = alloc(1024);
    float* W3cat = alloc(147456);     // contiguous init region start
    float* Ucat = alloc(589824);
    float* Tfr  = alloc(196608);
    float* Tfi  = alloc(196608);
    float* Tc   = alloc(196608);
    float* Rf   = alloc(65536);
    float* Rc   = alloc(65536);       // init region end
    float* Tw   = alloc(196608);
    float* chFr = alloc(65536); float* chFi = alloc(65536);
    float* QpFr = alloc(65536); float* QpFi = alloc(65536);
    float* chW  = alloc(65536); float* QpW  = alloc(65536);
    float* chC  = alloc(65536); float* QpC  = alloc(65536);
    float* OFr  = alloc(65536); float* OFi  = alloc(65536);
    float* Ow   = alloc(65536); float* Oc   = alloc(65536);
    float* Pt   = alloc(156672);
    float* Mten = alloc(41616);
    float* ybv  = alloc(1024);
    if (ws_size < off * sizeof(float)) return;

    float* Uf = Ucat, *Uw = Ucat + 196608, *Uc = Ucat + 2 * 196608;
    const long SE48 = 2048 * 48, SE16 = 2048 * 16;

    // ---- prep / folds ----
    prep_fw_G<<<dim3(3), dim3(256), 0, stream>>>(Fp[0], Fp[1], Fp[2], fw, Gm);
    build_w2<<<dim3(576), dim3(256), 0, stream>>>(Wc[0], Wc[1], Wc[2], W2cat);
    build_ub2<<<dim3(3), dim3(256), 0, stream>>>(bp[0], bp[1], bp[2], W2cat, ubv);
    init_bufs<<<dim3((147456 + 589824 + 720896 + 255) / 256), dim3(256), 0, stream>>>(W3cat, ubv);
    gen_trig<<<dim3(32768), dim3(256), 0, stream>>>(MAT0, MAT1, DCTD, DCTI);

    // W3_d = Wp_d^T @ W2_d  (one launch, sel = domain, KS=4)
    skinny_multi<48, true><<<dim3(16, 1, 12), dim3(256), 0, stream>>>(
        Wp[0], Wp[1], Wp[2],
        W2cat, W2cat + 49152, W2cat + 2 * 49152,
        W3cat, W3cat + 49152, W3cat + 2 * 49152,
        1024, 1024, 48, 48, 0, 0, 1.f, 1.f, 1.f, 1, 4);

    // U_d = query @ W3_d (+ub preloaded)
    skinny<48, false, false, true><<<dim3(64, 1, 6), dim3(256), 0, stream>>>(
        query, W3cat, Ucat, 1024, 1024, 48, 48, 0, 49152, 196608, 1.f, 2);

    // forward transforms (Tfr, Tfi, Tc) in one launch
    skinny_multi<48, false><<<dim3(32, 1, 24), dim3(256), 0, stream>>>(
        MAT0, MAT1, DCTD, Uf, Uf, Uc, Tfr, Tfi, Tc,
        2048, 2048, 48, 48, SE48, SE48, 1.f, 1.f, 1.f, 2, 4);

    // Haar pyramid (single kernel)
    haar_all<<<dim3(6, 2), dim3(256), 0, stream>>>(Uw, Tw);

    // conv collapse + G fold
    conv_mix2<true><<<dim3(32, 2), dim3(256), 0, stream>>>(Tfr, Tfi, Gm, bc[0], chFr, chFi, QpFr, QpFi);
    conv_mix2<false><<<dim3(32, 2), dim3(256), 0, stream>>>(Tw, nullptr, Gm + 256, bc[1], chW, nullptr, QpW, nullptr);
    conv_mix2<false><<<dim3(32, 2), dim3(256), 0, stream>>>(Tc, nullptr, Gm + 512, bc[2], chC, nullptr, QpC, nullptr);

    // flash attentions (wave per Q-row)
    flash_c2<<<dim3(512, 2), dim3(256), 0, stream>>>(QpFr, QpFi, chFr, chFi, OFr, OFi);
    flash_r2<<<dim3(512, 2), dim3(256), 0, stream>>>(QpW, chW, Ow);
    flash_r2<<<dim3(512, 2), dim3(256), 0, stream>>>(QpC, chC, Oc);

    // inverse transforms (Rf += MAT0@OFr + MAT1@OFi scaled; Rc = DCTI@Oc) one launch
    skinny_multi<16, false><<<dim3(32, 1, 24), dim3(256), 0, stream>>>(
        MAT0, MAT1, DCTI, OFr, OFi, Oc, Rf, Rf, Rc,
        2048, 2048, 16, 16, SE16, SE16, 1.f / 2048.f, 1.f / 2048.f, 1.f, 2, 4);

    // MHA folds
    skinny<16, false, true, false><<<dim3(48, 1, 3), dim3(256), 0, stream>>>(
        mha_iw, fw, Pt, 1024, 1024, 1024, 17, 0, 16384, 52224, 1.f, 1);
    ib_append<<<dim3(36), dim3(256), 0, stream>>>(mha_ib, Pt);
    build_M<<<dim3(144), dim3(256), 0, stream>>>(Pt, Mten);

    // MHA core -> MO (4096, 3072)
    mha_o<<<dim3(16, 16), dim3(256), 0, stream>>>(Rf, Ow, Rc, Pt, Mten, MO);

    // FT_l = fusW_l @ ow  (stored as (1024 x 3072) with l-slabs via batch)
    transpose_k<<<dim3(32, 32), dim3(256), 0, stream>>>(mha_ow, OWT, 1024, 1024);
    gemm(stream, fus_W, OWT, FTb, nullptr, 1024, 1024, 1024, 3072, 1024, 3072,
         1024, 0, 1024, 1.f, 0.f, 3);
    build_yb2<<<dim3(256), dim3(256), 0, stream>>>(mha_ob, fus_W, fus_b, ybv);

    // out = MO @ FTb^T + yb
    gemm(stream, MO, FTb, out, ybv, 4096, 1024, 3072, 3072, 3072, 1024,
         0, 0, 0, 1.f, 0.f, 1);
}

// Round 5
// 765.737 us; speedup vs baseline: 8.4852x; 1.1375x over previous
//
#include <hip/hip_runtime.h>
#include <cmath>

#define BB 2
#define SS_ 2048
#define EE 1024
#define CC 16

typedef __attribute__((ext_vector_type(8))) short short8v;
typedef __attribute__((ext_vector_type(4))) float floatx4;

__device__ __forceinline__ void split4(const float4 v, short4& h, short4& l)
{
    unsigned ux = __float_as_uint(v.x), uy = __float_as_uint(v.y);
    unsigned uz = __float_as_uint(v.z), uw = __float_as_uint(v.w);
    h.x = (short)(ux >> 16); h.y = (short)(uy >> 16);
    h.z = (short)(uz >> 16); h.w = (short)(uw >> 16);
    float lx = v.x - __uint_as_float(ux & 0xFFFF0000u);
    float ly = v.y - __uint_as_float(uy & 0xFFFF0000u);
    float lz = v.z - __uint_as_float(uz & 0xFFFF0000u);
    float lw = v.w - __uint_as_float(uw & 0xFFFF0000u);
    l.x = (short)(__float_as_uint(lx) >> 16);
    l.y = (short)(__float_as_uint(ly) >> 16);
    l.z = (short)(__float_as_uint(lz) >> 16);
    l.w = (short)(__float_as_uint(lw) >> 16);
}

// ---------------------------------------------------------------------------
// Split-bf16 MFMA GEMM, K-split + atomic epilogue: C += alpha * A @ B^T
// A (M,K) lda; B (N,K) ldb. z = bz*KS + ks. C must be pre-initialized.
// ---------------------------------------------------------------------------
#define BM 128
#define BN 128
#define BK 32
#define LDP 40

__launch_bounds__(256, 2)
__global__ void gemm_at(const float* __restrict__ A, const float* __restrict__ Bsrc,
                        float* __restrict__ C,
                        int K, int lda, int ldb, int ldc,
                        long sA, long sB, long sC, float alpha, int KS)
{
    __shared__ short sAh[BM * LDP], sAl[BM * LDP], sBh[BN * LDP], sBl[BN * LDP];
    const int z = blockIdx.z;
    const int bz = z / KS, ks = z % KS;
    const int klen = K / KS, kbase = ks * klen;
    A += (size_t)bz * sA; Bsrc += (size_t)bz * sB; C += (size_t)bz * sC;
    const int tid = threadIdx.x;
    const int m0 = blockIdx.y * BM, n0 = blockIdx.x * BN;

    const int lr0 = tid >> 3;
    const int kc0 = (tid & 7) * 4;
    const float* pa = A + (size_t)(m0 + lr0) * lda + kbase + kc0;
    const float* pb = Bsrc + (size_t)(n0 + lr0) * ldb + kbase + kc0;

    float4 ra[4], rb[4];
    #pragma unroll
    for (int c = 0; c < 4; ++c) {
        ra[c] = *(const float4*)(pa + (size_t)c * 32 * lda);
        rb[c] = *(const float4*)(pb + (size_t)c * 32 * ldb);
    }

    const int lane = tid & 63, wid = tid >> 6;
    const int wm = wid >> 1, wn = wid & 1;
    const int lr = lane & 15, qd = lane >> 4;
    const int arow = wm * 64 + lr;
    const int brow = wn * 64 + lr;
    const int koff = qd * 8;

    floatx4 acc[4][4];
    #pragma unroll
    for (int i = 0; i < 4; ++i)
        #pragma unroll
        for (int j = 0; j < 4; ++j)
            acc[i][j] = (floatx4){0.f, 0.f, 0.f, 0.f};

    for (int kt = 0; kt < klen; kt += BK) {
        __syncthreads();
        #pragma unroll
        for (int c = 0; c < 4; ++c) {
            const int row = lr0 + c * 32;
            short4 h, l;
            split4(ra[c], h, l);
            *(short4*)&sAh[row * LDP + kc0] = h;
            *(short4*)&sAl[row * LDP + kc0] = l;
            split4(rb[c], h, l);
            *(short4*)&sBh[row * LDP + kc0] = h;
            *(short4*)&sBl[row * LDP + kc0] = l;
        }
        __syncthreads();
        if (kt + BK < klen) {
            pa += BK; pb += BK;
            #pragma unroll
            for (int c = 0; c < 4; ++c) {
                ra[c] = *(const float4*)(pa + (size_t)c * 32 * lda);
                rb[c] = *(const float4*)(pb + (size_t)c * 32 * ldb);
            }
        }
        short8v ah[4], al[4], bh[4], bl[4];
        #pragma unroll
        for (int i = 0; i < 4; ++i) {
            ah[i] = *(const short8v*)&sAh[(arow + i * 16) * LDP + koff];
            al[i] = *(const short8v*)&sAl[(arow + i * 16) * LDP + koff];
            bh[i] = *(const short8v*)&sBh[(brow + i * 16) * LDP + koff];
            bl[i] = *(const short8v*)&sBl[(brow + i * 16) * LDP + koff];
        }
        #pragma unroll
        for (int i = 0; i < 4; ++i)
            #pragma unroll
            for (int j = 0; j < 4; ++j)
                acc[i][j] = __builtin_amdgcn_mfma_f32_16x16x32_bf16(ah[i], bh[j], acc[i][j], 0, 0, 0);
        #pragma unroll
        for (int i = 0; i < 4; ++i)
            #pragma unroll
            for (int j = 0; j < 4; ++j)
                acc[i][j] = __builtin_amdgcn_mfma_f32_16x16x32_bf16(ah[i], bl[j], acc[i][j], 0, 0, 0);
        #pragma unroll
        for (int i = 0; i < 4; ++i)
            #pragma unroll
            for (int j = 0; j < 4; ++j)
                acc[i][j] = __builtin_amdgcn_mfma_f32_16x16x32_bf16(al[i], bh[j], acc[i][j], 0, 0, 0);
    }

    #pragma unroll
    for (int i = 0; i < 4; ++i) {
        const int mbase = m0 + wm * 64 + i * 16 + qd * 4;
        #pragma unroll
        for (int j = 0; j < 4; ++j) {
            const int n = n0 + wn * 64 + j * 16 + lr;
            #pragma unroll
            for (int r = 0; r < 4; ++r)
                atomicAdd(&C[(size_t)(mbase + r) * ldc + n], alpha * acc[i][j][r]);
        }
    }
}

// ---------------------------------------------------------------------------
// Tall-skinny bf16x3 MFMA: C += alpha * A @ B. A (M,K) fp32, B (K,NT) fp32.
// MODE 0: C0 += al*A0@B0
// MODE 1: C0 += al*A0@B0 ; C1 += al*A1@B0          (dual-A, shared B)
// MODE 2: C0 += al*(A0@B0 + A1@B1)                 (dual-A dual-B, one acc)
// BM=64, BK=32, 256 thr = 4 waves x 16 rows. z = zb*KS + ks. Atomic epilogue.
// ---------------------------------------------------------------------------
template<int NT, int MODE>
__launch_bounds__(256, 4)
__global__ void skmfma(const float* __restrict__ A0, const float* __restrict__ A1,
                       const float* __restrict__ B0, const float* __restrict__ B1,
                       float* __restrict__ C0, float* __restrict__ C1,
                       int K, int lda, int ldb, int ldc,
                       long sA, long sB, long sC, float alpha, int KS)
{
    constexpr int NA = (MODE >= 1) ? 2 : 1;
    constexpr int NB = (MODE == 2) ? 2 : 1;
    constexpr int NACC = (MODE == 1) ? 2 : 1;
    constexpr int CT = NT / 16;
    __shared__ short sAh[NA][64 * 40], sAl[NA][64 * 40];
    __shared__ short sBh[NB][NT * 40], sBl[NB][NT * 40];
    const int z = blockIdx.z;
    const int zb = z / KS, ks = z % KS;
    const int klen = K / KS, kbase = ks * klen;
    const float* Ap[NA]; const float* Bp[NB]; float* Cp[NACC];
    Ap[0] = A0 + (size_t)zb * sA;
    if constexpr (NA == 2) Ap[1] = A1 + (size_t)zb * sA;
    Bp[0] = B0 + (size_t)zb * sB;
    if constexpr (NB == 2) Bp[1] = B1 + (size_t)zb * sB;
    Cp[0] = C0 + (size_t)zb * sC;
    if constexpr (NACC == 2) Cp[1] = C1 + (size_t)zb * sC;

    const int tid = threadIdx.x;
    const int m0 = blockIdx.x * 64;
    const int arow = tid >> 2, akc = (tid & 3) * 8;
    const int lane = tid & 63, w = tid >> 6;
    const int lr = lane & 15, qd = lane >> 4;

    floatx4 acc[NACC][CT];
    #pragma unroll
    for (int s = 0; s < NACC; ++s)
        #pragma unroll
        for (int j = 0; j < CT; ++j)
            acc[s][j] = (floatx4){0.f, 0.f, 0.f, 0.f};

    for (int kc = 0; kc < klen; kc += 32) {
        __syncthreads();
        #pragma unroll
        for (int s = 0; s < NA; ++s) {
            const float* pa = Ap[s] + (size_t)(m0 + arow) * lda + kbase + kc + akc;
            float4 v0 = *(const float4*)pa;
            float4 v1 = *(const float4*)(pa + 4);
            short4 h, l;
            split4(v0, h, l);
            *(short4*)&sAh[s][arow * 40 + akc] = h;
            *(short4*)&sAl[s][arow * 40 + akc] = l;
            split4(v1, h, l);
            *(short4*)&sAh[s][arow * 40 + akc + 4] = h;
            *(short4*)&sAl[s][arow * 40 + akc + 4] = l;
        }
        #pragma unroll
        for (int s = 0; s < NB; ++s) {
            for (int lin = tid; lin < 32 * (NT / 4); lin += 256) {
                int kk = lin / (NT / 4), n4 = (lin % (NT / 4)) * 4;
                float4 v = *(const float4*)(Bp[s] + (size_t)(kbase + kc + kk) * ldb + n4);
                short4 h, l; split4(v, h, l);
                sBh[s][(n4 + 0) * 40 + kk] = h.x; sBh[s][(n4 + 1) * 40 + kk] = h.y;
                sBh[s][(n4 + 2) * 40 + kk] = h.z; sBh[s][(n4 + 3) * 40 + kk] = h.w;
                sBl[s][(n4 + 0) * 40 + kk] = l.x; sBl[s][(n4 + 1) * 40 + kk] = l.y;
                sBl[s][(n4 + 2) * 40 + kk] = l.z; sBl[s][(n4 + 3) * 40 + kk] = l.w;
            }
        }
        __syncthreads();
        short8v ah[NA], alv[NA];
        #pragma unroll
        for (int s = 0; s < NA; ++s) {
            ah[s]  = *(const short8v*)&sAh[s][(w * 16 + lr) * 40 + qd * 8];
            alv[s] = *(const short8v*)&sAl[s][(w * 16 + lr) * 40 + qd * 8];
        }
        short8v bh[NB][CT], bl[NB][CT];
        #pragma unroll
        for (int s = 0; s < NB; ++s)
            #pragma unroll
            for (int j = 0; j < CT; ++j) {
                bh[s][j] = *(const short8v*)&sBh[s][(j * 16 + lr) * 40 + qd * 8];
                bl[s][j] = *(const short8v*)&sBl[s][(j * 16 + lr) * 40 + qd * 8];
            }
        if constexpr (MODE == 0) {
            #pragma unroll
            for (int j = 0; j < CT; ++j) {
                acc[0][j] = __builtin_amdgcn_mfma_f32_16x16x32_bf16(ah[0], bh[0][j], acc[0][j], 0, 0, 0);
                acc[0][j] = __builtin_amdgcn_mfma_f32_16x16x32_bf16(ah[0], bl[0][j], acc[0][j], 0, 0, 0);
                acc[0][j] = __builtin_amdgcn_mfma_f32_16x16x32_bf16(alv[0], bh[0][j], acc[0][j], 0, 0, 0);
            }
        } else if constexpr (MODE == 1) {
            #pragma unroll
            for (int j = 0; j < CT; ++j) {
                acc[0][j] = __builtin_amdgcn_mfma_f32_16x16x32_bf16(ah[0], bh[0][j], acc[0][j], 0, 0, 0);
                acc[0][j] = __builtin_amdgcn_mfma_f32_16x16x32_bf16(ah[0], bl[0][j], acc[0][j], 0, 0, 0);
                acc[0][j] = __builtin_amdgcn_mfma_f32_16x16x32_bf16(alv[0], bh[0][j], acc[0][j], 0, 0, 0);
                acc[1][j] = __builtin_amdgcn_mfma_f32_16x16x32_bf16(ah[1], bh[0][j], acc[1][j], 0, 0, 0);
                acc[1][j] = __builtin_amdgcn_mfma_f32_16x16x32_bf16(ah[1], bl[0][j], acc[1][j], 0, 0, 0);
                acc[1][j] = __builtin_amdgcn_mfma_f32_16x16x32_bf16(alv[1], bh[0][j], acc[1][j], 0, 0, 0);
            }
        } else {
            #pragma unroll
            for (int j = 0; j < CT; ++j) {
                acc[0][j] = __builtin_amdgcn_mfma_f32_16x16x32_bf16(ah[0], bh[0][j], acc[0][j], 0, 0, 0);
                acc[0][j] = __builtin_amdgcn_mfma_f32_16x16x32_bf16(ah[0], bl[0][j], acc[0][j], 0, 0, 0);
                acc[0][j] = __builtin_amdgcn_mfma_f32_16x16x32_bf16(alv[0], bh[0][j], acc[0][j], 0, 0, 0);
                acc[0][j] = __builtin_amdgcn_mfma_f32_16x16x32_bf16(ah[1], bh[1][j], acc[0][j], 0, 0, 0);
                acc[0][j] = __builtin_amdgcn_mfma_f32_16x16x32_bf16(ah[1], bl[1][j], acc[0][j], 0, 0, 0);
                acc[0][j] = __builtin_amdgcn_mfma_f32_16x16x32_bf16(alv[1], bh[1][j], acc[0][j], 0, 0, 0);
            }
        }
    }
    #pragma unroll
    for (int s = 0; s < NACC; ++s)
        #pragma unroll
        for (int j = 0; j < CT; ++j) {
            const int n = j * 16 + lr;
            const int mb = m0 + w * 16 + qd * 4;
            #pragma unroll
            for (int r = 0; r < 4; ++r)
                atomicAdd(&Cp[s][(size_t)(mb + r) * ldc + n], alpha * acc[s][j][r]);
        }
}

// ---------------------------------------------------------------------------
// Trig matrices (DFT + DCT in one launch)
// ---------------------------------------------------------------------------
__global__ void gen_trig(float* __restrict__ Cc, float* __restrict__ Sn,
                         float* __restrict__ D, float* __restrict__ I)
{
    size_t idx = (size_t)blockIdx.x * 256 + threadIdx.x;
    if (idx < 4194304) {
        int k = (int)(idx >> 11);
        int n = (int)(idx & 2047);
        int m = (k * n) & 2047;
        float ang = (float)(6.283185307179586 * (double)m / 2048.0);
        Cc[idx] = cosf(ang);
        Sn[idx] = -sinf(ang);
    } else {
        idx -= 4194304;
        int i = (int)(idx >> 11);
        int j = (int)(idx & 2047);
        const float r1 = 0.022097086912079608f;
        const float r2 = 0.03125f;
        const float pif = 3.14159265358979323846f;
        float a  = (pif * (float)i) * (float)(2 * j + 1) / 4096.0f;
        D[idx] = cosf(a) * (i == 0 ? r1 : r2);
        float ai = (pif * (float)j) * (float)(2 * i + 1) / 4096.0f;
        I[idx] = cosf(ai) * (j == 0 ? r1 : r2);
    }
}

// ---------------------------------------------------------------------------
// fw softmax (stored transposed, e-major) + G = (1/32) fw@fw^T. grid 3.
// ---------------------------------------------------------------------------
__launch_bounds__(256)
__global__ void prep_fw_G(const float* __restrict__ F0, const float* __restrict__ F1,
                          const float* __restrict__ F2, float* __restrict__ fwT,
                          float* __restrict__ G)
{
    const int d = blockIdx.x, tid = threadIdx.x;
    const float* Fp = d == 0 ? F0 : (d == 1 ? F1 : F2);
    __shared__ float sf[CC * 1028];
    #pragma unroll
    for (int k = 0; k < 4; ++k) {
        int e = tid + k * 256;
        float v[CC]; float m = -3.4e38f;
        #pragma unroll
        for (int c = 0; c < CC; ++c) { v[c] = Fp[c * EE + e]; m = fmaxf(m, v[c]); }
        float s = 0.f;
        #pragma unroll
        for (int c = 0; c < CC; ++c) { v[c] = expf(v[c] - m); s += v[c]; }
        float inv = 1.f / s;
        #pragma unroll
        for (int c = 0; c < CC; ++c) { v[c] *= inv; sf[c * 1028 + e] = v[c]; }
        #pragma unroll
        for (int j = 0; j < 4; ++j)
            *(float4*)(fwT + d * 16384 + (size_t)e * 16 + j * 4) = *(float4*)&v[j * 4];
    }
    __syncthreads();
    const int a = tid >> 4, b = tid & 15;
    const float4* pa = (const float4*)&sf[a * 1028];
    const float4* pb = (const float4*)&sf[b * 1028];
    float s = 0.f;
    for (int i = 0; i < 256; ++i) {
        float4 x = pa[i], y = pb[i];
        s += x.x * y.x + x.y * y.y + x.z * y.z + x.w * y.w;
    }
    G[d * 256 + a * 16 + b] = s * 0.03125f;
}

__global__ void build_w2(const float* __restrict__ W0, const float* __restrict__ W1,
                         const float* __restrict__ W2_, float* __restrict__ W2cat)
{
    int idx = blockIdx.x * 256 + threadIdx.x;
    if (idx >= 3 * CC * EE * 3) return;
    int d = idx / 49152, r = idx % 49152;
    const float* Wc = d == 0 ? W0 : (d == 1 ? W1 : W2_);
    int c = r / 3072, e = (r % 3072) / 3, k = r % 3;
    W2cat[d * 49152 + e * 48 + c * 3 + k] = Wc[r];
}

__global__ void build_ub2(const float* __restrict__ b0, const float* __restrict__ b1,
                          const float* __restrict__ b2, const float* __restrict__ W2cat,
                          float* __restrict__ ub)
{
    const int d = blockIdx.x, tid = threadIdx.x;
    const float* bp = d == 0 ? b0 : (d == 1 ? b1 : b2);
    __shared__ float red[4][48];
    const int c = tid & 63, sl = tid >> 6;
    float s = 0.f;
    if (c < 48)
        for (int e = sl; e < EE; e += 4)
            s += bp[e] * W2cat[d * 49152 + e * 48 + c];
    if (c < 48) red[sl][c] = s;
    __syncthreads();
    if (tid < 48) ub[d * 48 + tid] = red[0][tid] + red[1][tid] + red[2][tid] + red[3][tid];
}

__launch_bounds__(256)
__global__ void build_yb2(const float* __restrict__ ob, const float* __restrict__ fus_W,
                          const float* __restrict__ fus_b, float* __restrict__ yb)
{
    const int n = blockIdx.x * 4 + (threadIdx.x >> 6);
    const int lane = threadIdx.x & 63;
    float s = 0.f;
    for (int j = lane; j < 3072; j += 64)
        s += ob[j & 1023] * fus_W[(size_t)n * 3072 + j];
    #pragma unroll
    for (int off = 32; off > 0; off >>= 1) s += __shfl_xor(s, off, 64);
    if (lane == 0) yb[n] = s + fus_b[n];
}

// init: [W3cat 0 | Ucat=ub | Tfr,Tfi,Tc,Rf,Rc 0] + Pt 0 + FTb 0 + out=yb
__global__ void init_all(float* __restrict__ zone1, const float* __restrict__ ub,
                         float* __restrict__ Pt, float* __restrict__ FTb,
                         float* __restrict__ out, const float* __restrict__ yb)
{
    size_t idx = (size_t)blockIdx.x * 256 + threadIdx.x;
    const size_t W3N = 147456, UN = 589824, ZN = 720896;
    const size_t Z1 = W3N + UN + ZN;                 // 1458176
    const size_t PTN = 156672, FTN = 3145728, ON = 4194304;
    if (idx < Z1) {
        float v = 0.f;
        if (idx >= W3N && idx < W3N + UN) {
            size_t r = idx - W3N;
            int d = (int)(r / 196608), c = (int)(r % 48);
            v = ub[d * 48 + c];
        }
        zone1[idx] = v;
    } else if (idx < Z1 + PTN) {
        Pt[idx - Z1] = 0.f;
    } else if (idx < Z1 + PTN + FTN) {
        FTb[idx - Z1 - PTN] = 0.f;
    } else if (idx < Z1 + PTN + FTN + ON) {
        size_t r = idx - Z1 - PTN - FTN;
        out[r] = yb[r & 1023];
    }
}

__global__ void ib_append(const float* __restrict__ ib, float* __restrict__ Pt)
{
    int idx = blockIdx.x * 256 + threadIdx.x;
    if (idx >= 9216) return;
    int d = idx / 3072, j = idx % 3072;
    Pt[d * 52224 + j * 17 + 16] = ib[j];
}

__launch_bounds__(256)
__global__ void build_M(const float* __restrict__ Pt, float* __restrict__ Mten)
{
    int blk = blockIdx.x;             // h*9 + l*3 + m
    int h = blk / 9, lm = blk % 9;
    int l = lm / 3, m = lm % 3;
    __shared__ float sQ[64][17], sK[64][17];
    for (int lin = threadIdx.x; lin < 1088; lin += 256) {
        int d = lin / 17, a = lin % 17;
        sQ[d][a] = Pt[l * 52224 + (size_t)(h * 64 + d) * 17 + a];
        sK[d][a] = Pt[m * 52224 + (size_t)(1024 + h * 64 + d) * 17 + a];
    }
    __syncthreads();
    for (int o = threadIdx.x; o < 289; o += 256) {
        int a = o / 17, b = o % 17;
        float s = 0.f;
        for (int d = 0; d < 64; ++d) s += sQ[d][a] * sK[d][b];
        Mten[(size_t)blk * 289 + o] = 0.125f * s;
    }
}

__global__ void transpose_k(const float* __restrict__ X, float* __restrict__ XT,
                            int rows, int cols)
{
    __shared__ float tile[32][33];
    const int lx = threadIdx.x & 31, ly = threadIdx.x >> 5;
    const int r0 = blockIdx.y * 32, c0 = blockIdx.x * 32;
    #pragma unroll
    for (int p = 0; p < 4; ++p)
        tile[ly + p * 8][lx] = X[(size_t)(r0 + ly + p * 8) * cols + c0 + lx];
    __syncthreads();
    #pragma unroll
    for (int p = 0; p < 4; ++p)
        XT[(size_t)(c0 + ly + p * 8) * rows + r0 + lx] = tile[lx][ly + p * 8];
}

__global__ void transpose_wp3(const float* __restrict__ W0, const float* __restrict__ W1,
                              const float* __restrict__ W2, float* __restrict__ WT)
{
    __shared__ float tile[32][33];
    const float* X = blockIdx.z == 0 ? W0 : (blockIdx.z == 1 ? W1 : W2);
    float* T = WT + (size_t)blockIdx.z * 1048576;
    const int lx = threadIdx.x & 31, ly = threadIdx.x >> 5;
    const int r0 = blockIdx.y * 32, c0 = blockIdx.x * 32;
    #pragma unroll
    for (int p = 0; p < 4; ++p)
        tile[ly + p * 8][lx] = X[(size_t)(r0 + ly + p * 8) * 1024 + c0 + lx];
    __syncthreads();
    #pragma unroll
    for (int p = 0; p < 4; ++p)
        T[(size_t)(c0 + ly + p * 8) * 1024 + r0 + lx] = tile[lx][ly + p * 8];
}

// ---------------------------------------------------------------------------
// Full Haar pyramid, one kernel. grid (48/HCG, B).
// ---------------------------------------------------------------------------
#define HCG 4
__launch_bounds__(256)
__global__ void haar_all(const float* __restrict__ U, float* __restrict__ T)
{
    __shared__ float A[2048 * HCG];
    __shared__ float Pp[1024 * HCG];
    const int g = blockIdx.x, b = blockIdx.y, tid = threadIdx.x;
    const float isq = 0.70710678118654752440f;
    for (int lin = tid; lin < 2048; lin += 256)
        *(float4*)&A[lin * 4] = *(const float4*)(U + ((size_t)(b * 2048 + lin)) * 48 + g * HCG);
    __syncthreads();
    float* cur = A; float* nxt = Pp;
    for (int h = 1024; h >= 1; h >>= 1) {
        for (int lin = tid; lin < h * HCG; lin += 256) {
            int i = lin >> 2, c = lin & 3;
            float e = cur[(2 * i) * HCG + c], o = cur[(2 * i + 1) * HCG + c];
            T[((size_t)(b * 2048 + h + i)) * 48 + g * HCG + c] = (e - o) * isq;
            nxt[i * HCG + c] = (e + o) * isq;
        }
        __syncthreads();
        float* t = cur; cur = nxt; nxt = t;
    }
    if (tid < HCG) T[((size_t)(b * 2048)) * 48 + g * HCG + tid] = cur[tid];
}

// ---------------------------------------------------------------------------
// conv collapse + G fold, all 3 domains in one launch. grid (32, B, 3).
// ---------------------------------------------------------------------------
__launch_bounds__(256)
__global__ void conv_all(const float* __restrict__ Tfr, const float* __restrict__ Tfi,
                         const float* __restrict__ Tw, const float* __restrict__ Tc,
                         const float* __restrict__ Gm,
                         const float* __restrict__ bc0, const float* __restrict__ bc1,
                         const float* __restrict__ bc2,
                         float* __restrict__ chFr, float* __restrict__ chFi,
                         float* __restrict__ chW, float* __restrict__ chC,
                         float* __restrict__ QFr, float* __restrict__ QFi,
                         float* __restrict__ QW, float* __restrict__ QC)
{
    const int dom = blockIdx.z;
    const bool cplx = (dom == 0);
    const float* Tre = dom == 0 ? Tfr : (dom == 1 ? Tw : Tc);
    const float* Tim = Tfi;
    const float* G = Gm + dom * 256;
    const float* bc = dom == 0 ? bc0 : (dom == 1 ? bc1 : bc2);
    float* chR = dom == 0 ? chFr : (dom == 1 ? chW : chC);
    float* chI = chFi;
    float* QR = dom == 0 ? QFr : (dom == 1 ? QW : QC);
    float* QI = QFi;

    const int s0 = blockIdx.x * 64, b = blockIdx.y;
    const int tid = threadIdx.x;
    __shared__ float sR[66 * 49];
    __shared__ float sI[66 * 49];
    __shared__ float scr[64 * 17];
    __shared__ float sci[64 * 17];
    __shared__ float sG[256];
    if (tid < 256) sG[tid] = G[tid];
    for (int lin = tid; lin < 66 * 12; lin += 256) {
        int r = lin / 12, c4 = (lin % 12) * 4;
        int srow = s0 - 1 + r;
        float4 v = {0.f, 0.f, 0.f, 0.f}, w = {0.f, 0.f, 0.f, 0.f};
        if (srow >= 0 && srow < 2048) {
            v = *(const float4*)(Tre + ((size_t)(b * 2048 + srow)) * 48 + c4);
            if (cplx) w = *(const float4*)(Tim + ((size_t)(b * 2048 + srow)) * 48 + c4);
        }
        sR[r * 49 + c4] = v.x; sR[r * 49 + c4 + 1] = v.y;
        sR[r * 49 + c4 + 2] = v.z; sR[r * 49 + c4 + 3] = v.w;
        if (cplx) {
            sI[r * 49 + c4] = w.x; sI[r * 49 + c4 + 1] = w.y;
            sI[r * 49 + c4 + 2] = w.z; sI[r * 49 + c4 + 3] = w.w;
        }
    }
    __syncthreads();
    const int row = tid >> 2, ln = tid & 3;
    float ch[4], chi[4];
    #pragma unroll
    for (int j = 0; j < 4; ++j) {
        int c = ln * 4 + j;
        float bcv = bc[c];
        ch[j] = sR[row * 49 + 3 * c] + sR[(row + 1) * 49 + 3 * c + 1]
              + sR[(row + 2) * 49 + 3 * c + 2] + bcv;
        scr[row * 17 + c] = ch[j];
        if (cplx) {
            chi[j] = sI[row * 49 + 3 * c] + sI[(row + 1) * 49 + 3 * c + 1]
                   + sI[(row + 2) * 49 + 3 * c + 2] + bcv;
            sci[row * 17 + c] = chi[j];
        }
    }
    size_t ro = ((size_t)(b * 2048 + s0 + row)) * 16 + ln * 4;
    *(float4*)(chR + ro) = *(float4*)&ch[0];
    if (cplx) *(float4*)(chI + ro) = *(float4*)&chi[0];
    __syncthreads();
    float qp[4] = {}, qpi[4] = {};
    #pragma unroll
    for (int c = 0; c < 16; ++c) {
        float cv = scr[row * 17 + c];
        float cvi = cplx ? sci[row * 17 + c] : 0.f;
        #pragma unroll
        for (int j = 0; j < 4; ++j) {
            float g = sG[c * 16 + ln * 4 + j];
            qp[j] = fmaf(cv, g, qp[j]);
            if (cplx) qpi[j] = fmaf(cvi, g, qpi[j]);
        }
    }
    *(float4*)(QR + ro) = *(float4*)&qp[0];
    if (cplx) *(float4*)(QI + ro) = *(float4*)&qpi[0];
}

// ---------------------------------------------------------------------------
// Flash attention rank-16, all 3 domains in one launch. grid (512, B, 3).
// z=0: complex; z=1: wavelet real; z=2: cosine real.
// ---------------------------------------------------------------------------
__launch_bounds__(256)
__global__ void flash_all(const float* __restrict__ QpFr, const float* __restrict__ QpFi,
                          const float* __restrict__ chFr, const float* __restrict__ chFi,
                          float* __restrict__ OFr, float* __restrict__ OFi,
                          const float* __restrict__ QpW, const float* __restrict__ chW,
                          float* __restrict__ Ow_,
                          const float* __restrict__ QpC, const float* __restrict__ chC,
                          float* __restrict__ Oc_)
{
    const int dom = blockIdx.z;
    const int b = blockIdx.y;
    const int w = threadIdx.x >> 6, lane = threadIdx.x & 63;
    const int s = blockIdx.x * 4 + w;
    if (dom != 0) {
        const float* Qp = dom == 1 ? QpW : QpC;
        const float* ch = dom == 1 ? chW : chC;
        float* O = dom == 1 ? Ow_ : Oc_;
        const float* qrow = Qp + ((size_t)(b * 2048 + s)) * 16;
        float q[16];
        #pragma unroll
        for (int j = 0; j < 4; ++j) *(float4*)&q[j * 4] = *(const float4*)(qrow + j * 4);
        const float* chb = ch + (size_t)b * 2048 * 16;
        float m = -3.4e38f, l = 0.f;
        float acc[16] = {};
        for (int t = lane; t < 2048; t += 64) {
            const float* kp = chb + (size_t)t * 16;
            float kv[16];
            #pragma unroll
            for (int j = 0; j < 4; ++j) *(float4*)&kv[j * 4] = *(const float4*)(kp + j * 4);
            float sc = 0.f;
            #pragma unroll
            for (int e = 0; e < 16; ++e) sc = fmaf(q[e], kv[e], sc);
            float mn = fmaxf(m, sc);
            float al = __expf(m - mn), p = __expf(sc - mn);
            l = l * al + p;
            #pragma unroll
            for (int e = 0; e < 16; ++e) acc[e] = fmaf(acc[e], al, p * kv[e]);
            m = mn;
        }
        #pragma unroll
        for (int off = 1; off < 64; off <<= 1) {
            float m2 = __shfl_xor(m, off, 64);
            float l2 = __shfl_xor(l, off, 64);
            float mn = fmaxf(m, m2);
            float ra = __expf(m - mn), rb = __expf(m2 - mn);
            l = l * ra + l2 * rb;
            #pragma unroll
            for (int e = 0; e < 16; ++e) {
                float a2 = __shfl_xor(acc[e], off, 64);
                acc[e] = acc[e] * ra + a2 * rb;
            }
            m = mn;
        }
        if (lane < 4) {
            float inv = 1.f / l;
            float4 o4 = {acc[lane * 4] * inv, acc[lane * 4 + 1] * inv,
                         acc[lane * 4 + 2] * inv, acc[lane * 4 + 3] * inv};
            *(float4*)(O + ((size_t)(b * 2048 + s)) * 16 + lane * 4) = o4;
        }
        return;
    }
    // complex
    float qr[16], qi[16];
    {
        const float* qrow = QpFr + ((size_t)(b * 2048 + s)) * 16;
        const float* qrowI = QpFi + ((size_t)(b * 2048 + s)) * 16;
        #pragma unroll
        for (int j = 0; j < 4; ++j) {
            *(float4*)&qr[j * 4] = *(const float4*)(qrow + j * 4);
            *(float4*)&qi[j * 4] = *(const float4*)(qrowI + j * 4);
        }
    }
    const float* cbR = chFr + (size_t)b * 2048 * 16;
    const float* cbI = chFi + (size_t)b * 2048 * 16;
    float m = -3.4e38f, l = 0.f;
    float aR[16] = {}, aI[16] = {};
    for (int t = lane; t < 2048; t += 64) {
        float kr[16], ki[16];
        #pragma unroll
        for (int j = 0; j < 4; ++j) {
            *(float4*)&kr[j * 4] = *(const float4*)(cbR + (size_t)t * 16 + j * 4);
            *(float4*)&ki[j * 4] = *(const float4*)(cbI + (size_t)t * 16 + j * 4);
        }
        float sre = 0.f, sim = 0.f;
        #pragma unroll
        for (int e = 0; e < 16; ++e) {
            sre = fmaf(qr[e], kr[e], sre); sre = fmaf(-qi[e], ki[e], sre);
            sim = fmaf(qr[e], ki[e], sim); sim = fmaf(qi[e], kr[e], sim);
        }
        float mn = fmaxf(m, sre);
        float al = __expf(m - mn), p = __expf(sre - mn);
        l = l * al + p;
        float rr = sqrtf(sre * sre + sim * sim);
        float iv = (rr > 0.f) ? (p / rr) : 0.f;
        float wr = (rr > 0.f) ? iv * sre : p;
        float wi = (rr > 0.f) ? iv * sim : 0.f;
        #pragma unroll
        for (int e = 0; e < 16; ++e) {
            aR[e] = fmaf(aR[e], al, wr * kr[e] - wi * ki[e]);
            aI[e] = fmaf(aI[e], al, wr * ki[e] + wi * kr[e]);
        }
        m = mn;
    }
    #pragma unroll
    for (int off = 1; off < 64; off <<= 1) {
        float m2 = __shfl_xor(m, off, 64);
        float l2 = __shfl_xor(l, off, 64);
        float mn = fmaxf(m, m2);
        float ra = __expf(m - mn), rb = __expf(m2 - mn);
        l = l * ra + l2 * rb;
        #pragma unroll
        for (int e = 0; e < 16; ++e) {
            float a2 = __shfl_xor(aR[e], off, 64);
            aR[e] = aR[e] * ra + a2 * rb;
            float b2 = __shfl_xor(aI[e], off, 64);
            aI[e] = aI[e] * ra + b2 * rb;
        }
        m = mn;
    }
    float inv = 1.f / l;
    size_t ro = ((size_t)(b * 2048 + s)) * 16;
    if (lane < 4) {
        float4 o4 = {aR[lane * 4] * inv, aR[lane * 4 + 1] * inv,
                     aR[lane * 4 + 2] * inv, aR[lane * 4 + 3] * inv};
        *(float4*)(OFr + ro + lane * 4) = o4;
    } else if (lane < 8) {
        int j = lane - 4;
        float4 o4 = {aI[j * 4] * inv, aI[j * 4 + 1] * inv,
                     aI[j * 4 + 2] * inv, aI[j * 4 + 3] * inv};
        *(float4*)(OFi + ro + j * 4) = o4;
    }
}

// ---------------------------------------------------------------------------
// MHA over L=3 via rank-17 bilinear forms -> MO (4096, 3072). grid (16,16).
// ---------------------------------------------------------------------------
__launch_bounds__(256)
__global__ void mha_o(const float* __restrict__ R0, const float* __restrict__ R1,
                      const float* __restrict__ R2, const float* __restrict__ Pt,
                      const float* __restrict__ Mten, float* __restrict__ MO)
{
    const int tid = threadIdx.x;
    const int p = blockIdx.x * 256 + tid;
    const int h = blockIdx.y;
    __shared__ float sPv[3 * 64 * 20];
    __shared__ float sM[9 * 17 * 20];
    for (int lin = tid; lin < 3264; lin += 256) {
        int mm = lin / 1088, rem = lin % 1088;
        int rr = rem / 17, a = rem % 17;
        sPv[(mm * 64 + rr) * 20 + a] = Pt[mm * 52224 + (size_t)(2048 + h * 64 + rr) * 17 + a];
    }
    for (int lin = tid; lin < 2601; lin += 256) {
        int lm = lin / 289, rem = lin % 289;
        int a = rem / 17, bq = rem % 17;
        sM[lm * 340 + a * 20 + bq] = Mten[(size_t)h * 2601 + lin];
    }
    __syncthreads();
    float R[3][16];
    float4 R4[3][4];
    #pragma unroll
    for (int j = 0; j < 4; ++j) {
        R4[0][j] = *(const float4*)(R0 + (size_t)p * 16 + j * 4);
        R4[1][j] = *(const float4*)(R1 + (size_t)p * 16 + j * 4);
        R4[2][j] = *(const float4*)(R2 + (size_t)p * 16 + j * 4);
        *(float4*)&R[0][j * 4] = R4[0][j];
        *(float4*)&R[1][j * 4] = R4[1][j];
        *(float4*)&R[2][j * 4] = R4[2][j];
    }
    float w[3][3];
    #pragma unroll
    for (int l = 0; l < 3; ++l) {
        float sc[3];
        #pragma unroll
        for (int mm = 0; mm < 3; ++mm) {
            const float* Mp = &sM[(l * 3 + mm) * 340];
            float s = 0.f;
            #pragma unroll
            for (int a = 0; a < 17; ++a) {
                const float* mr = Mp + a * 20;
                float4 m0 = *(const float4*)(mr), m1 = *(const float4*)(mr + 4);
                float4 m2 = *(const float4*)(mr + 8), m3 = *(const float4*)(mr + 12);
                float t = mr[16];
                t = fmaf(m0.x, R4[mm][0].x, t); t = fmaf(m0.y, R4[mm][0].y, t);
                t = fmaf(m0.z, R4[mm][0].z, t); t = fmaf(m0.w, R4[mm][0].w, t);
                t = fmaf(m1.x, R4[mm][1].x, t); t = fmaf(m1.y, R4[mm][1].y, t);
                t = fmaf(m1.z, R4[mm][1].z, t); t = fmaf(m1.w, R4[mm][1].w, t);
                t = fmaf(m2.x, R4[mm][2].x, t); t = fmaf(m2.y, R4[mm][2].y, t);
                t = fmaf(m2.z, R4[mm][2].z, t); t = fmaf(m2.w, R4[mm][2].w, t);
                t = fmaf(m3.x, R4[mm][3].x, t); t = fmaf(m3.y, R4[mm][3].y, t);
                t = fmaf(m3.z, R4[mm][3].z, t); t = fmaf(m3.w, R4[mm][3].w, t);
                float ra = (a < 16) ? R[l][a] : 1.f;
                s = fmaf(ra, t, s);
            }
            sc[mm] = s;
        }
        float mx = fmaxf(sc[0], fmaxf(sc[1], sc[2]));
        float e0 = expf(sc[0] - mx), e1 = expf(sc[1] - mx), e2 = expf(sc[2] - mx);
        float inv = 1.f / (e0 + e1 + e2);
        w[l][0] = e0 * inv; w[l][1] = e1 * inv; w[l][2] = e2 * inv;
    }
    #pragma unroll
    for (int d4 = 0; d4 < 16; ++d4) {
        float4 vm[3];
        #pragma unroll
        for (int mm = 0; mm < 3; ++mm) {
            float vx[4];
            #pragma unroll
            for (int r = 0; r < 4; ++r) {
                const float* pv = &sPv[(mm * 64 + d4 * 4 + r) * 20];
                float4 p0 = *(const float4*)(pv), p1 = *(const float4*)(pv + 4);
                float4 p2 = *(const float4*)(pv + 8), p3 = *(const float4*)(pv + 12);
                float t = pv[16];
                t = fmaf(R4[mm][0].x, p0.x, t); t = fmaf(R4[mm][0].y, p0.y, t);
                t = fmaf(R4[mm][0].z, p0.z, t); t = fmaf(R4[mm][0].w, p0.w, t);
                t = fmaf(R4[mm][1].x, p1.x, t); t = fmaf(R4[mm][1].y, p1.y, t);
                t = fmaf(R4[mm][1].z, p1.z, t); t = fmaf(R4[mm][1].w, p1.w, t);
                t = fmaf(R4[mm][2].x, p2.x, t); t = fmaf(R4[mm][2].y, p2.y, t);
                t = fmaf(R4[mm][2].z, p2.z, t); t = fmaf(R4[mm][2].w, p2.w, t);
                t = fmaf(R4[mm][3].x, p3.x, t); t = fmaf(R4[mm][3].y, p3.y, t);
                t = fmaf(R4[mm][3].z, p3.z, t); t = fmaf(R4[mm][3].w, p3.w, t);
                vx[r] = t;
            }
            vm[mm] = (float4){vx[0], vx[1], vx[2], vx[3]};
        }
        #pragma unroll
        for (int l = 0; l < 3; ++l) {
            float4 o4;
            o4.x = w[l][0] * vm[0].x + w[l][1] * vm[1].x + w[l][2] * vm[2].x;
            o4.y = w[l][0] * vm[0].y + w[l][1] * vm[1].y + w[l][2] * vm[2].y;
            o4.z = w[l][0] * vm[0].z + w[l][1] * vm[1].z + w[l][2] * vm[2].z;
            o4.w = w[l][0] * vm[0].w + w[l][1] * vm[1].w + w[l][2] * vm[2].w;
            *(float4*)(MO + (size_t)p * 3072 + l * 1024 + h * 64 + d4 * 4) = o4;
        }
    }
}

// ---------------------------------------------------------------------------
// Host
// ---------------------------------------------------------------------------
extern "C" void kernel_launch(void* const* d_in, const int* in_sizes, int n_in,
                              void* d_out, int out_size, void* d_ws, size_t ws_size,
                              hipStream_t stream)
{
    const float* query = (const float*)d_in[0];
    const float* Wp[3] = {(const float*)d_in[1], (const float*)d_in[6],  (const float*)d_in[11]};
    const float* bp[3] = {(const float*)d_in[2], (const float*)d_in[7],  (const float*)d_in[12]};
    const float* Wc[3] = {(const float*)d_in[3], (const float*)d_in[8],  (const float*)d_in[13]};
    const float* bc[3] = {(const float*)d_in[4], (const float*)d_in[9],  (const float*)d_in[14]};
    const float* Fp[3] = {(const float*)d_in[5], (const float*)d_in[10], (const float*)d_in[15]};
    const float* mha_iw = (const float*)d_in[16];
    const float* mha_ib = (const float*)d_in[17];
    const float* mha_ow = (const float*)d_in[18];
    const float* mha_ob = (const float*)d_in[19];
    const float* fus_W  = (const float*)d_in[20];
    const float* fus_b  = (const float*)d_in[21];
    float* out = (float*)d_out;
    float* ws = (float*)d_ws;

    size_t off = 0;
    auto alloc = [&](size_t n) { float* p = ws + off; off += n; return p; };
    float* MAT0 = alloc(4194304);
    float* MAT1 = alloc(4194304);
    float* DCTD = alloc(4194304);
    float* DCTI = alloc(4194304);
    float* MO   = alloc((size_t)4096 * 3072);
    float* FTb  = alloc((size_t)1024 * 3072);
    float* OWT  = alloc((size_t)1024 * 1024);
    float* WpT  = alloc(3145728);
    float* fwT  = alloc(49152);
    float* W2cat = alloc(147456);
    float* ubv  = alloc(256);
    float* Gm   = alloc(1024);
    float* W3cat = alloc(147456);     // contiguous init region start
    float* Ucat = alloc(589824);
    float* Tfr  = alloc(196608);
    float* Tfi  = alloc(196608);
    float* Tc   = alloc(196608);
    float* Rf   = alloc(65536);
    float* Rc   = alloc(65536);       // init region end
    float* Tw   = alloc(196608);
    float* chFr = alloc(65536); float* chFi = alloc(65536);
    float* QpFr = alloc(65536); float* QpFi = alloc(65536);
    float* chW  = alloc(65536); float* QpW  = alloc(65536);
    float* chC  = alloc(65536); float* QpC  = alloc(65536);
    float* OFr  = alloc(65536); float* OFi  = alloc(65536);
    float* Ow   = alloc(65536); float* Oc   = alloc(65536);
    float* Pt   = alloc(156672);
    float* Mten = alloc(41616);
    float* ybv  = alloc(1024);
    if (ws_size < off * sizeof(float)) return;

    float* Uf = Ucat, *Uw = Ucat + 196608, *Uc = Ucat + 2 * 196608;
    const long SE48 = 2048 * 48, SE16 = 2048 * 16;

    // ---- prep ----
    build_w2<<<dim3(576), dim3(256), 0, stream>>>(Wc[0], Wc[1], Wc[2], W2cat);
    prep_fw_G<<<dim3(3), dim3(256), 0, stream>>>(Fp[0], Fp[1], Fp[2], fwT, Gm);
    build_ub2<<<dim3(3), dim3(256), 0, stream>>>(bp[0], bp[1], bp[2], W2cat, ubv);
    build_yb2<<<dim3(256), dim3(256), 0, stream>>>(mha_ob, fus_W, fus_b, ybv);
    gen_trig<<<dim3(32768), dim3(256), 0, stream>>>(MAT0, MAT1, DCTD, DCTI);
    transpose_wp3<<<dim3(32, 32, 3), dim3(256), 0, stream>>>(Wp[0], Wp[1], Wp[2], WpT);
    init_all<<<dim3(34980), dim3(256), 0, stream>>>(W3cat, ubv, Pt, FTb, out, ybv);

    // ---- skinny MFMA products ----
    // W3_d = Wp_d^T @ W2_d
    skmfma<48, 0><<<dim3(16, 1, 6), dim3(256), 0, stream>>>(
        WpT, nullptr, W2cat, nullptr, W3cat, nullptr,
        1024, 1024, 48, 48, 1048576, 49152, 49152, 1.f, 2);
    // U_d = query @ W3_d (+ub preloaded)
    skmfma<48, 0><<<dim3(64, 1, 6), dim3(256), 0, stream>>>(
        query, nullptr, W3cat, nullptr, Ucat, nullptr,
        1024, 1024, 48, 48, 0, 49152, 196608, 1.f, 2);
    // Fourier fwd: Tfr = MAT0@Uf, Tfi = MAT1@Uf (dual-A)
    skmfma<48, 1><<<dim3(32, 1, 8), dim3(256), 0, stream>>>(
        MAT0, MAT1, Uf, nullptr, Tfr, Tfi,
        2048, 2048, 48, 48, 0, SE48, SE48, 1.f, 4);
    // DCT fwd: Tc = DCTD@Uc
    skmfma<48, 0><<<dim3(32, 1, 8), dim3(256), 0, stream>>>(
        DCTD, nullptr, Uc, nullptr, Tc, nullptr,
        2048, 2048, 48, 48, 0, SE48, SE48, 1.f, 4);

    // Haar pyramid
    haar_all<<<dim3(12, 2), dim3(256), 0, stream>>>(Uw, Tw);

    // conv collapse + G fold (all domains)
    conv_all<<<dim3(32, 2, 3), dim3(256), 0, stream>>>(
        Tfr, Tfi, Tw, Tc, Gm, bc[0], bc[1], bc[2],
        chFr, chFi, chW, chC, QpFr, QpFi, QpW, QpC);

    // flash attentions (all domains)
    flash_all<<<dim3(512, 2, 3), dim3(256), 0, stream>>>(
        QpFr, QpFi, chFr, chFi, OFr, OFi, QpW, chW, Ow, QpC, chC, Oc);

    // Fourier inv: Rf = (1/S)(MAT0@OFr + MAT1@OFi)  (dual-A dual-B)
    skmfma<16, 2><<<dim3(32, 1, 8), dim3(256), 0, stream>>>(
        MAT0, MAT1, OFr, OFi, Rf, nullptr,
        2048, 2048, 16, 16, 0, SE16, SE16, 1.f / 2048.f, 4);
    // DCT inv: Rc = DCTI@Oc
    skmfma<16, 0><<<dim3(32, 1, 8), dim3(256), 0, stream>>>(
        DCTI, nullptr, Oc, nullptr, Rc, nullptr,
        2048, 2048, 16, 16, 0, SE16, SE16, 1.f, 4);
    // Pt_l = mha_iw @ fwT_l (cols 0..15 of pitch-17 Pt)
    skmfma<16, 0><<<dim3(48, 1, 6), dim3(256), 0, stream>>>(
        mha_iw, nullptr, fwT, nullptr, Pt, nullptr,
        1024, 1024, 16, 17, 0, 16384, 52224, 1.f, 2);

    ib_append<<<dim3(36), dim3(256), 0, stream>>>(mha_ib, Pt);
    build_M<<<dim3(144), dim3(256), 0, stream>>>(Pt, Mten);

    // MHA core -> MO (4096, 3072)
    mha_o<<<dim3(16, 16), dim3(256), 0, stream>>>(Rf, Ow, Rc, Pt, Mten, MO);

    // FT_l = fusW_l @ ow  (atomic K-split, FTb pre-zeroed)
    transpose_k<<<dim3(32, 32), dim3(256), 0, stream>>>(mha_ow, OWT, 1024, 1024);
    gemm_at<<<dim3(8, 8, 6), dim3(256), 0, stream>>>(
        fus_W, OWT, FTb, 1024, 3072, 1024, 3072, 1024, 0, 1024, 1.f, 2);

    // out = MO @ FTb^T + yb  (out pre-initialized with yb; atomic K-split)
    gemm_at<<<dim3(8, 32, 2), dim3(256), 0, stream>>>(
        MO, FTb, out, 3072, 3072, 3072, 1024, 0, 0, 0, 1.f, 2);
}